// Round 13
// baseline (253.289 us; speedup 1.0000x reference)
//
#include <hip/hip_runtime.h>
#include <math.h>

#define BB 32
#define TT 2048
#define DD 1024
#define NH 16
#define HDIM 64
#define EPS 1e-5f

// ---------------- reduction helpers ----------------
__device__ __forceinline__ float wredSum(float v){
  v += __shfl_down(v, 32, 64);
  v += __shfl_down(v, 16, 64);
  v += __shfl_down(v, 8, 64);
  v += __shfl_down(v, 4, 64);
  v += __shfl_down(v, 2, 64);
  v += __shfl_down(v, 1, 64);
  return v;
}
__device__ float bredSum(float v, float* red){
  int lane = threadIdx.x & 63, w = threadIdx.x >> 6, nw = blockDim.x >> 6;
  v = wredSum(v);
  __syncthreads();
  if (lane == 0) red[w] = v;
  __syncthreads();
  if (w == 0){
    float x = (lane < nw) ? red[lane] : 0.f;
    x = wredSum(x);
    if (lane == 0) red[0] = x;
  }
  __syncthreads();
  return red[0];
}

// ---------------- K0a: q = LN(h_t)*tau ----------------
__global__ __launch_bounds__(256) void k_qln(const float* __restrict__ h_t,
   const float* __restrict__ g, const float* __restrict__ bb,
   const float* __restrict__ log_tau, float* __restrict__ q)
{
  int b = blockIdx.x, tid = threadIdx.x;
  __shared__ float red[64];
  float4 x = ((const float4*)(h_t + (size_t)b*DD))[tid];
  float s = x.x + x.y + x.z + x.w;
  s = bredSum(s, red);
  float mu = s * (1.f/DD);
  float d0=x.x-mu, d1=x.y-mu, d2=x.z-mu, d3=x.w-mu;
  float s2 = d0*d0 + d1*d1 + d2*d2 + d3*d3;
  s2 = bredSum(s2, red);
  float rs = rsqrtf(s2*(1.f/DD) + EPS);
  float tau = fminf(fmaxf(expf(log_tau[0]), 0.25f), 4.0f);
  float4 gv = ((const float4*)g)[tid], bv = ((const float4*)bb)[tid];
  float4 o;
  o.x = (d0*rs*gv.x + bv.x)*tau;
  o.y = (d1*rs*gv.y + bv.y)*tau;
  o.z = (d2*rs*gv.z + bv.z)*tau;
  o.w = (d3*rs*gv.w + bv.w)*tau;
  ((float4*)(q + (size_t)b*DD))[tid] = o;
}

// ------------- small GEMM (32x1024 @ 1024x1024^T), d-split partials -------------
__global__ __launch_bounds__(256) void k_gemmsplit(const float* __restrict__ A,
    const float* __restrict__ W, float* __restrict__ p2)
{
  int ec = blockIdx.x, ds = blockIdx.y;
  int tid = threadIdx.x;
  __shared__ float Wl[64][132];
  __shared__ float Al[32][132];
  int d0 = ds*128, e0 = ec*64;
#pragma unroll
  for (int p=0;p<8;p++){
    int fi = p*256 + tid, r = fi >> 5, q4 = fi & 31;
    float4 v = *(const float4*)(W + (size_t)(e0+r)*DD + d0 + q4*4);
    *(float4*)&Wl[r][q4*4] = v;
  }
#pragma unroll
  for (int p=0;p<4;p++){
    int fi = p*256 + tid, r = fi >> 5, q4 = fi & 31;
    float4 v = *(const float4*)(A + (size_t)r*DD + d0 + q4*4);
    *(float4*)&Al[r][q4*4] = v;
  }
  __syncthreads();
  int eL = tid & 63, bg = tid >> 6;
  float acc[8];
#pragma unroll
  for (int i=0;i<8;i++) acc[i]=0.f;
  for (int d4=0; d4<32; d4++){
    float4 w = *(float4*)&Wl[eL][d4*4];
#pragma unroll
    for (int i=0;i<8;i++){
      float4 a = *(float4*)&Al[bg*8+i][d4*4];
      acc[i] = fmaf(w.x, a.x, acc[i]);
      acc[i] = fmaf(w.y, a.y, acc[i]);
      acc[i] = fmaf(w.z, a.z, acc[i]);
      acc[i] = fmaf(w.w, a.w, acc[i]);
    }
  }
#pragma unroll
  for (int i=0;i<8;i++)
    p2[((size_t)ds*BB + (bg*8+i))*DD + e0 + eL] = acc[i];
}

// ------------- K0c: qh-reduce + s = Wk_h^T qh_h ; gs2, gsum, cst -------------
__global__ __launch_bounds__(256) void k_prep_s(const float* __restrict__ p2,
    const float* __restrict__ Wfull, const float* __restrict__ bfull,
    const float* __restrict__ g_kv, const float* __restrict__ b_kv,
    float* __restrict__ gs2, float* __restrict__ gsum, float* __restrict__ cst)
{
  int h = blockIdx.x, b = blockIdx.y;
  int tid = threadIdx.x;
  __shared__ float qhl[64];
  __shared__ float red[64];
  if (tid < 64){
    float s = bfull[h*HDIM + tid];   // bq
#pragma unroll
    for (int k=0;k<8;k++)
      s += p2[((size_t)k*BB + b)*DD + h*HDIM + tid];
    qhl[tid] = s;
  }
  __syncthreads();
  int d0 = tid*4;
  const float* Wk = Wfull + (size_t)DD*DD + (size_t)h*HDIM*DD + d0;
  float4 acc = make_float4(0.f,0.f,0.f,0.f);
#pragma unroll
  for (int j=0;j<64;j++){
    float qv = qhl[j];
    float4 w = *(const float4*)(Wk + (size_t)j*DD);
    acc.x = fmaf(qv, w.x, acc.x);
    acc.y = fmaf(qv, w.y, acc.y);
    acc.z = fmaf(qv, w.z, acc.z);
    acc.w = fmaf(qv, w.w, acc.w);
  }
  float4 gk = *(const float4*)(g_kv + d0);
  float4 bk = *(const float4*)(b_kv + d0);
  float4 gsv;
  gsv.x = acc.x*gk.x; gsv.y = acc.y*gk.y;
  gsv.z = acc.z*gk.z; gsv.w = acc.w*gk.w;
  int hq = h >> 2, hj = h & 3;
  float* gp = gs2 + (((size_t)b*4 + hq)*DD + d0)*4 + hj;
  gp[0] = gsv.x; gp[4] = gsv.y; gp[8] = gsv.z; gp[12] = gsv.w;
  float lgs = gsv.x + gsv.y + gsv.z + gsv.w;
  float lbs = acc.x*bk.x + acc.y*bk.y + acc.z*bk.z + acc.w*bk.w;
  float lc = 0.f;
  if (tid < 64) lc = qhl[tid] * bfull[DD + h*HDIM + tid];  // qh . bk-bias
  float tg = bredSum(lgs, red);
  float tb = bredSum(lbs + lc, red);
  if (tid == 0){ gsum[b*NH+h] = tg; cst[b*NH+h] = tb; }
}

// ------------- K1: FUSED full-D scores + local softmax + u-partial accumulation -------------
// Pass 1 (= R10 structure): 64 t-rows x 1024 d; (row,hq) threads; X+g double-buffered LDS.
// Then: alpha_local = exp(sc - m_chunk)*rs staged in LDS [h][t]; pass 2 re-reads X
// (L2/L3-hot) accumulating u_c[16][1024] chunk partials. pm holds (m,S,B) per chunk.
#define SR 64
#define SDC 64
#define NCH (DD/SDC)
__global__ __launch_bounds__(256, 4) void k_scores(
    const float* __restrict__ X, const int* __restrict__ valid,
    const float* __restrict__ gs2, const float* __restrict__ gsum,
    const float* __restrict__ cst,
    float* __restrict__ pm, float* __restrict__ part)
{
  int tc = blockIdx.x, b = blockIdx.y;
  int t0 = tc * SR;
  int vb = valid[b];
  if (t0 >= vb) return;
  int tid = threadIdx.x;
  int row = tid & 63, rx = row & 15;
  int hq = __builtin_amdgcn_readfirstlane(tid >> 6);
  __shared__ float4 xt[2][SR*16];    // 16KB x2, swizzle u = cg ^ (r&15)
  __shared__ float4 gt[2][4*64];     // 4KB x2: [hq][d]; reused as alpha after pass 1
  const float* xb = X + ((size_t)b*TT + t0)*DD;
  const float4* gq4 = (const float4*)gs2 + ((size_t)b*4 + hq)*DD;
  int r0 = tid >> 4, cg0 = tid & 15;
  float4 ld0, ld1, ld2, ld3, gld;
  float a0=0.f, a1=0.f, a2=0.f, a3=0.f, ssum=0.f, ssq=0.f;
#define LOADC(c) { const float* pb = xb + (c)*SDC; \
    ld0 = *(const float4*)(pb + (size_t)(r0+ 0)*DD + cg0*4); \
    ld1 = *(const float4*)(pb + (size_t)(r0+16)*DD + cg0*4); \
    ld2 = *(const float4*)(pb + (size_t)(r0+32)*DD + cg0*4); \
    ld3 = *(const float4*)(pb + (size_t)(r0+48)*DD + cg0*4); \
    gld = gq4[(c)*64 + row]; }
#define STOREC(c) { float4* tb2 = xt[(c)&1]; int u = cg0 ^ r0; \
    tb2[(r0+ 0)*16 + u] = ld0; \
    tb2[(r0+16)*16 + u] = ld1; \
    tb2[(r0+32)*16 + u] = ld2; \
    tb2[(r0+48)*16 + u] = ld3; \
    gt[(c)&1][hq*64 + row] = gld; }

  LOADC(0);
  STOREC(0);
  for (int c = 0; c < NCH; ++c){
    if (c+1 < NCH) LOADC(c+1);
    __syncthreads();
    {
      const float4* tb = xt[c&1] + row*16;
      const float4* gb = gt[c&1] + hq*64;
#pragma unroll 4
      for (int d4=0; d4<16; d4++){
        float4 xv = tb[d4 ^ rx];
        float4 g0 = gb[d4*4+0];
        float4 g1 = gb[d4*4+1];
        float4 g2 = gb[d4*4+2];
        float4 g3 = gb[d4*4+3];
        ssum += xv.x + xv.y + xv.z + xv.w;
        ssq = fmaf(xv.x,xv.x,ssq); ssq = fmaf(xv.y,xv.y,ssq);
        ssq = fmaf(xv.z,xv.z,ssq); ssq = fmaf(xv.w,xv.w,ssq);
        a0 = fmaf(xv.x,g0.x,a0); a1 = fmaf(xv.x,g0.y,a1);
        a2 = fmaf(xv.x,g0.z,a2); a3 = fmaf(xv.x,g0.w,a3);
        a0 = fmaf(xv.y,g1.x,a0); a1 = fmaf(xv.y,g1.y,a1);
        a2 = fmaf(xv.y,g1.z,a2); a3 = fmaf(xv.y,g1.w,a3);
        a0 = fmaf(xv.z,g2.x,a0); a1 = fmaf(xv.z,g2.y,a1);
        a2 = fmaf(xv.z,g2.z,a2); a3 = fmaf(xv.z,g2.w,a3);
        a0 = fmaf(xv.w,g3.x,a0); a1 = fmaf(xv.w,g3.y,a1);
        a2 = fmaf(xv.w,g3.z,a2); a3 = fmaf(xv.w,g3.w,a3);
      }
    }
    if (c+1 < NCH){
      __syncthreads();
      STOREC(c+1);
    }
  }
#undef LOADC
#undef STOREC
  float mu = ssum * (1.f/DD);
  float rs = rsqrtf(ssq*(1.f/DD) - mu*mu + EPS);
  int t = t0 + row;
  float4 gq = *(const float4*)(gsum + b*NH + hq*4);
  float4 cq = *(const float4*)(cst  + b*NH + hq*4);
  float4 sc;
  sc.x = (rs*(a0 - mu*gq.x) + cq.x)*0.125f;
  sc.y = (rs*(a1 - mu*gq.y) + cq.y)*0.125f;
  sc.z = (rs*(a2 - mu*gq.z) + cq.z)*0.125f;
  sc.w = (rs*(a3 - mu*gq.w) + cq.w)*0.125f;

  // per-chunk online-softmax partials (masked beyond valid)
  bool act = (t < vb);
  float m0 = act ? sc.x : -3.0e38f;
  float m1 = act ? sc.y : -3.0e38f;
  float m2 = act ? sc.z : -3.0e38f;
  float m3 = act ? sc.w : -3.0e38f;
#pragma unroll
  for (int off=32; off>=1; off>>=1){
    m0 = fmaxf(m0, __shfl_xor(m0, off, 64));
    m1 = fmaxf(m1, __shfl_xor(m1, off, 64));
    m2 = fmaxf(m2, __shfl_xor(m2, off, 64));
    m3 = fmaxf(m3, __shfl_xor(m3, off, 64));
  }
  float rm = rs*mu;
  float e0 = act ? expf(sc.x - m0) : 0.f;
  float e1 = act ? expf(sc.y - m1) : 0.f;
  float e2 = act ? expf(sc.z - m2) : 0.f;
  float e3 = act ? expf(sc.w - m3) : 0.f;
  float S0=e0, S1=e1, S2=e2, S3=e3;
  float B0=e0*rm, B1=e1*rm, B2=e2*rm, B3=e3*rm;
#pragma unroll
  for (int off=32; off>=1; off>>=1){
    S0 += __shfl_xor(S0, off, 64);
    S1 += __shfl_xor(S1, off, 64);
    S2 += __shfl_xor(S2, off, 64);
    S3 += __shfl_xor(S3, off, 64);
    B0 += __shfl_xor(B0, off, 64);
    B1 += __shfl_xor(B1, off, 64);
    B2 += __shfl_xor(B2, off, 64);
    B3 += __shfl_xor(B3, off, 64);
  }
  if (row == 0){
    float* pb = pm + ((size_t)(b*(TT/SR) + tc)*3)*16 + hq*4;
    pb[0]=m0;  pb[1]=m1;  pb[2]=m2;  pb[3]=m3;
    pb[16]=S0; pb[17]=S1; pb[18]=S2; pb[19]=S3;
    pb[32]=B0; pb[33]=B1; pb[34]=B2; pb[35]=B3;
  }

  // ---- stage local alpha = exp(sc-m_c)*rs into LDS [h][t] (conflict-free) ----
  float* alds = (float*)gt;   // 4KB: [16 h][64 t]; gt[0] half unused by last compute
  alds[(hq*4+0)*64 + row] = e0 * rs;
  alds[(hq*4+1)*64 + row] = e1 * rs;
  alds[(hq*4+2)*64 + row] = e2 * rs;
  alds[(hq*4+3)*64 + row] = e3 * rs;
  __syncthreads();

  // ---- pass 2: u_c[h][d] = sum_t alpha[h][t] * X[t][d]; thread owns 4 d ----
  float4 u[16];
#pragma unroll
  for (int h=0;h<16;h++) u[h] = make_float4(0.f,0.f,0.f,0.f);
  const float4* xr4 = (const float4*)xb;
  float4 xv = xr4[tid];
  for (int tl=0; tl<64; tl++){
    float4 cur = xv;
    if (tl < 63) xv = xr4[(tl+1)*256 + tid];
    float av[16];
#pragma unroll
    for (int h=0;h<16;h++) av[h] = alds[h*64 + tl];
#pragma unroll
    for (int h=0;h<16;h++){
      u[h].x = fmaf(av[h], cur.x, u[h].x);
      u[h].y = fmaf(av[h], cur.y, u[h].y);
      u[h].z = fmaf(av[h], cur.z, u[h].z);
      u[h].w = fmaf(av[h], cur.w, u[h].w);
    }
  }
  float* pp = part + ((size_t)(tc*BB + b)*NH)*DD;
#pragma unroll
  for (int h=0;h<16;h++)
    ((float4*)(pp + (size_t)h*DD))[tid] = u[h];
}

// ------------- K4: u-merge (w_c-weighted) + beta + ctx = Wv_h @ u + bv -------------
// Wl in 128-d chunks ([64][133] pad)
__global__ __launch_bounds__(256) void k_uctx(const float* __restrict__ part,
   const int* __restrict__ valid, const float* __restrict__ pm,
   const float* __restrict__ g_kv, const float* __restrict__ b_kv,
   const float* __restrict__ Wfull, const float* __restrict__ bfull,
   float* __restrict__ ctx)
{
  int h = blockIdx.x, b = blockIdx.y;
  int tid = threadIdx.x;
  __shared__ float ul[DD];
  __shared__ float Wl[64][133];
  __shared__ float red2[4][64];
  __shared__ float wc[TT/SR];
  __shared__ float bsh;
  int vb = valid[b];
  int nch = (vb + SR - 1)/SR;
  // ---- wave-0: merge pm -> M,S,B; chunk weights wc[c] = exp(m_c - M)/S ----
  if (tid < 64){
    float M0=-3.0e38f, S=0.f, Bv=0.f;
    if (tid < nch){
      const float* pb = pm + ((size_t)(b*(TT/SR) + tid))*48;
      M0 = pb[h]; S = pb[16+h]; Bv = pb[32+h];
    }
    float M = M0;
#pragma unroll
    for (int off=32; off>=1; off>>=1){
      float om = __shfl_down(M, off, 64);
      float oS = __shfl_down(S, off, 64);
      float oB = __shfl_down(Bv, off, 64);
      float Mn = fmaxf(M, om);
      float f1 = expf(M - Mn), f2 = expf(om - Mn);
      S  = S*f1 + oS*f2;
      Bv = Bv*f1 + oB*f2;
      M = Mn;
    }
    float Mt = __shfl(M, 0, 64);
    float St = __shfl(S, 0, 64);
    float Bt = __shfl(Bv, 0, 64);
    if (tid < nch) wc[tid] = expf(M0 - Mt) / St;
    if (tid == 0) bsh = Bt / St;
  }
  __syncthreads();
  // ---- weighted chunk merge ----
  int d = tid*4;
  float4 s = make_float4(0.f,0.f,0.f,0.f);
  for (int c=0;c<nch;c++){
    float w = wc[c];
    float4 v = *(const float4*)(part + (((size_t)c*BB + b)*NH + h)*DD + d);
    s.x = fmaf(w, v.x, s.x);
    s.y = fmaf(w, v.y, s.y);
    s.z = fmaf(w, v.z, s.z);
    s.w = fmaf(w, v.w, s.w);
  }
  {
    float be = bsh;
    float4 g = *(const float4*)(g_kv + d);
    float4 bv = *(const float4*)(b_kv + d);
    float4 r;
    r.x = fmaf(g.x, s.x-be, bv.x);
    r.y = fmaf(g.y, s.y-be, bv.y);
    r.z = fmaf(g.z, s.z-be, bv.z);
    r.w = fmaf(g.w, s.w-be, bv.w);
    ((float4*)ul)[tid] = r;
  }
  __syncthreads();
  int j = tid & 63, quart = tid >> 6;
  float acc = 0.f;
  const float* Wv = Wfull + (size_t)2*DD*DD;
  for (int dc=0; dc<DD; dc+=128){
#pragma unroll
    for (int p=0;p<8;p++){
      int fi = p*256 + tid, r = fi >> 5, q4 = fi & 31;
      float4 v = *(const float4*)(Wv + (size_t)(h*HDIM + r)*DD + dc + q4*4);
      Wl[r][q4*4+0]=v.x; Wl[r][q4*4+1]=v.y; Wl[r][q4*4+2]=v.z; Wl[r][q4*4+3]=v.w;
    }
    __syncthreads();
#pragma unroll
    for (int i=0;i<32;i++)
      acc = fmaf(Wl[j][quart*32+i], ul[dc + quart*32 + i], acc);
    __syncthreads();
  }
  red2[quart][j] = acc;
  __syncthreads();
  if (quart == 0){
    float v = red2[0][j] + red2[1][j] + red2[2][j] + red2[3][j];
    ctx[(size_t)b*DD + h*HDIM + j] = v + bfull[2*DD + h*HDIM + j];
  }
}

// ------------- K5: fused out-proj reduce + out = LN(o + h_t) -------------
__global__ __launch_bounds__(256) void k_outln(const float* __restrict__ p2,
   const float* __restrict__ obias, const float* __restrict__ h_t,
   const float* __restrict__ g, const float* __restrict__ bb,
   float* __restrict__ out)
{
  int b = blockIdx.x, tid = threadIdx.x;
  __shared__ float red[64];
  int e = tid*4;
  float4 a = *(const float4*)(obias + e);
#pragma unroll
  for (int k=0;k<8;k++){
    float4 v = *(const float4*)(p2 + ((size_t)k*BB + b)*DD + e);
    a.x+=v.x; a.y+=v.y; a.z+=v.z; a.w+=v.w;
  }
  float4 r = ((const float4*)(h_t + (size_t)b*DD))[tid];
  a.x+=r.x; a.y+=r.y; a.z+=r.z; a.w+=r.w;
  float s = a.x + a.y + a.z + a.w;
  s = bredSum(s, red);
  float mu = s * (1.f/DD);
  float d0=a.x-mu, d1=a.y-mu, d2=a.z-mu, d3=a.w-mu;
  float s2 = d0*d0 + d1*d1 + d2*d2 + d3*d3;
  s2 = bredSum(s2, red);
  float rs = rsqrtf(s2*(1.f/DD) + EPS);
  float4 gv = ((const float4*)g)[tid], bv = ((const float4*)bb)[tid];
  float4 ov;
  ov.x = fmaf(d0*rs, gv.x, bv.x);
  ov.y = fmaf(d1*rs, gv.y, bv.y);
  ov.z = fmaf(d2*rs, gv.z, bv.z);
  ov.w = fmaf(d3*rs, gv.w, bv.w);
  ((float4*)(out + (size_t)b*DD))[tid] = ov;
}

extern "C" void kernel_launch(void* const* d_in, const int* in_sizes, int n_in,
                              void* d_out, int out_size, void* d_ws, size_t ws_size,
                              hipStream_t stream) {
  const float* h_t     = (const float*)d_in[0];
  const float* H_p     = (const float*)d_in[1];
  const int*   valid   = (const int*)  d_in[2];
  const float* ln_q_g  = (const float*)d_in[3];
  const float* ln_q_b  = (const float*)d_in[4];
  const float* ln_kv_g = (const float*)d_in[5];
  const float* ln_kv_b = (const float*)d_in[6];
  const float* ln_out_g= (const float*)d_in[7];
  const float* ln_out_b= (const float*)d_in[8];
  const float* log_tau = (const float*)d_in[9];
  const float* in_w    = (const float*)d_in[10];
  const float* in_b    = (const float*)d_in[11];
  const float* out_w   = (const float*)d_in[12];
  const float* out_b   = (const float*)d_in[13];
  float* out = (float*)d_out;

  float* ws     = (float*)d_ws;
  float* q      = ws;
  float* gs2    = q      + BB*DD;
  float* gsum   = gs2    + (size_t)BB*DD*NH;
  float* cst    = gsum   + BB*NH;
  float* ctx    = cst    + BB*NH;
  float* pm     = ctx    + BB*DD;
  float* part   = pm     + (size_t)BB*(TT/SR)*48;
  // part: 32 chunks x B x NH x D = 64MB; time-shared with in-proj/out-proj
  // gemm partials (p2, 1MB, consumed before/after the attention phase).

  k_qln<<<BB, 256, 0, stream>>>(h_t, ln_q_g, ln_q_b, log_tau, q);
  k_gemmsplit<<<dim3(16,8), 256, 0, stream>>>(q, in_w, part);
  k_prep_s<<<dim3(NH,BB), 256, 0, stream>>>(part, in_w, in_b, ln_kv_g, ln_kv_b, gs2, gsum, cst);
  k_scores<<<dim3(TT/SR,BB), 256, 0, stream>>>(H_p, valid, gs2, gsum, cst, pm, part);
  k_uctx<<<dim3(NH,BB), 256, 0, stream>>>(part, valid, pm, ln_kv_g, ln_kv_b, in_w, in_b, ctx);
  k_gemmsplit<<<dim3(16,8), 256, 0, stream>>>(ctx, out_w, part);
  k_outln<<<BB, 256, 0, stream>>>(part, out_b, h_t, ln_out_g, ln_out_b, out);
}

// Round 14
// 147.047 us; speedup vs baseline: 1.7225x; 1.7225x over previous
//
#include <hip/hip_runtime.h>
#include <math.h>

#define BB 32
#define TT 2048
#define DD 1024
#define NH 16
#define HDIM 64
#define EPS 1e-5f

// ---------------- reduction helpers ----------------
__device__ __forceinline__ float wredSum(float v){
  v += __shfl_down(v, 32, 64);
  v += __shfl_down(v, 16, 64);
  v += __shfl_down(v, 8, 64);
  v += __shfl_down(v, 4, 64);
  v += __shfl_down(v, 2, 64);
  v += __shfl_down(v, 1, 64);
  return v;
}
__device__ float bredSum(float v, float* red){
  int lane = threadIdx.x & 63, w = threadIdx.x >> 6, nw = blockDim.x >> 6;
  v = wredSum(v);
  __syncthreads();
  if (lane == 0) red[w] = v;
  __syncthreads();
  if (w == 0){
    float x = (lane < nw) ? red[lane] : 0.f;
    x = wredSum(x);
    if (lane == 0) red[0] = x;
  }
  __syncthreads();
  return red[0];
}

// ---------------- K0a: q = LN(h_t)*tau ----------------
__global__ __launch_bounds__(256) void k_qln(const float* __restrict__ h_t,
   const float* __restrict__ g, const float* __restrict__ bb,
   const float* __restrict__ log_tau, float* __restrict__ q)
{
  int b = blockIdx.x, tid = threadIdx.x;
  __shared__ float red[64];
  float4 x = ((const float4*)(h_t + (size_t)b*DD))[tid];
  float s = x.x + x.y + x.z + x.w;
  s = bredSum(s, red);
  float mu = s * (1.f/DD);
  float d0=x.x-mu, d1=x.y-mu, d2=x.z-mu, d3=x.w-mu;
  float s2 = d0*d0 + d1*d1 + d2*d2 + d3*d3;
  s2 = bredSum(s2, red);
  float rs = rsqrtf(s2*(1.f/DD) + EPS);
  float tau = fminf(fmaxf(expf(log_tau[0]), 0.25f), 4.0f);
  float4 gv = ((const float4*)g)[tid], bv = ((const float4*)bb)[tid];
  float4 o;
  o.x = (d0*rs*gv.x + bv.x)*tau;
  o.y = (d1*rs*gv.y + bv.y)*tau;
  o.z = (d2*rs*gv.z + bv.z)*tau;
  o.w = (d3*rs*gv.w + bv.w)*tau;
  ((float4*)(q + (size_t)b*DD))[tid] = o;
}

// ------------- small GEMM (32x1024 @ 1024x1024^T), d-split partials -------------
__global__ __launch_bounds__(256) void k_gemmsplit(const float* __restrict__ A,
    const float* __restrict__ W, float* __restrict__ p2)
{
  int ec = blockIdx.x, ds = blockIdx.y;
  int tid = threadIdx.x;
  __shared__ float Wl[64][132];
  __shared__ float Al[32][132];
  int d0 = ds*128, e0 = ec*64;
#pragma unroll
  for (int p=0;p<8;p++){
    int fi = p*256 + tid, r = fi >> 5, q4 = fi & 31;
    float4 v = *(const float4*)(W + (size_t)(e0+r)*DD + d0 + q4*4);
    *(float4*)&Wl[r][q4*4] = v;
  }
#pragma unroll
  for (int p=0;p<4;p++){
    int fi = p*256 + tid, r = fi >> 5, q4 = fi & 31;
    float4 v = *(const float4*)(A + (size_t)r*DD + d0 + q4*4);
    *(float4*)&Al[r][q4*4] = v;
  }
  __syncthreads();
  int eL = tid & 63, bg = tid >> 6;
  float acc[8];
#pragma unroll
  for (int i=0;i<8;i++) acc[i]=0.f;
  for (int d4=0; d4<32; d4++){
    float4 w = *(float4*)&Wl[eL][d4*4];
#pragma unroll
    for (int i=0;i<8;i++){
      float4 a = *(float4*)&Al[bg*8+i][d4*4];
      acc[i] = fmaf(w.x, a.x, acc[i]);
      acc[i] = fmaf(w.y, a.y, acc[i]);
      acc[i] = fmaf(w.z, a.z, acc[i]);
      acc[i] = fmaf(w.w, a.w, acc[i]);
    }
  }
#pragma unroll
  for (int i=0;i<8;i++)
    p2[((size_t)ds*BB + (bg*8+i))*DD + e0 + eL] = acc[i];
}

// ------------- K0c: qh-reduce + s = Wk_h^T qh_h ; gs2, gsum, cst -------------
// Thread owns 4 CONSECUTIVE d (float4 Wk loads), fully unrolled j.
// gs2 layout: [b][hq][d][4h].
__global__ __launch_bounds__(256) void k_prep_s(const float* __restrict__ p2,
    const float* __restrict__ Wfull, const float* __restrict__ bfull,
    const float* __restrict__ g_kv, const float* __restrict__ b_kv,
    float* __restrict__ gs2, float* __restrict__ gsum, float* __restrict__ cst)
{
  int h = blockIdx.x, b = blockIdx.y;
  int tid = threadIdx.x;
  __shared__ float qhl[64];
  __shared__ float red[64];
  if (tid < 64){
    float s = bfull[h*HDIM + tid];   // bq
#pragma unroll
    for (int k=0;k<8;k++)
      s += p2[((size_t)k*BB + b)*DD + h*HDIM + tid];
    qhl[tid] = s;
  }
  __syncthreads();
  int d0 = tid*4;
  const float* Wk = Wfull + (size_t)DD*DD + (size_t)h*HDIM*DD + d0;
  float4 acc = make_float4(0.f,0.f,0.f,0.f);
#pragma unroll
  for (int j=0;j<64;j++){
    float qv = qhl[j];
    float4 w = *(const float4*)(Wk + (size_t)j*DD);
    acc.x = fmaf(qv, w.x, acc.x);
    acc.y = fmaf(qv, w.y, acc.y);
    acc.z = fmaf(qv, w.z, acc.z);
    acc.w = fmaf(qv, w.w, acc.w);
  }
  float4 gk = *(const float4*)(g_kv + d0);
  float4 bk = *(const float4*)(b_kv + d0);
  float4 gsv;
  gsv.x = acc.x*gk.x; gsv.y = acc.y*gk.y;
  gsv.z = acc.z*gk.z; gsv.w = acc.w*gk.w;
  int hq = h >> 2, hj = h & 3;
  float* gp = gs2 + (((size_t)b*4 + hq)*DD + d0)*4 + hj;
  gp[0] = gsv.x; gp[4] = gsv.y; gp[8] = gsv.z; gp[12] = gsv.w;
  float lgs = gsv.x + gsv.y + gsv.z + gsv.w;
  float lbs = acc.x*bk.x + acc.y*bk.y + acc.z*bk.z + acc.w*bk.w;
  float lc = 0.f;
  if (tid < 64) lc = qhl[tid] * bfull[DD + h*HDIM + tid];  // qh . bk-bias
  float tg = bredSum(lgs, red);
  float tb = bredSum(lbs + lc, red);
  if (tid == 0){ gsum[b*NH+h] = tg; cst[b*NH+h] = tb; }
}

// ------------- K1: full-D scores + chunk-partial online softmax (R10) -------------
// 64 t-rows x full 1024 d; 256 threads = (row, hq); gt LDS staging (broadcast
// reads), 40KB LDS -> 4 blocks/CU, (256,4).
#define SR 64
#define SDC 64
#define NCH (DD/SDC)
__global__ __launch_bounds__(256, 4) void k_scores(
    const float* __restrict__ X, const int* __restrict__ valid,
    const float* __restrict__ gs2, const float* __restrict__ gsum,
    const float* __restrict__ cst,
    float4* __restrict__ pacc, float* __restrict__ rs_arr,
    float* __restrict__ pm)
{
  int tc = blockIdx.x, b = blockIdx.y;
  int t0 = tc * SR;
  int vb = valid[b];
  if (t0 >= vb) return;
  int tid = threadIdx.x;
  int row = tid & 63, rx = row & 15;
  int hq = __builtin_amdgcn_readfirstlane(tid >> 6);
  __shared__ float4 xt[2][SR*16];    // 16KB x2, swizzle u = cg ^ (r&15)
  __shared__ float4 gt[2][4*64];     // 4KB x2: [hq][d]
  const float* xb = X + ((size_t)b*TT + t0)*DD;
  const float4* gq4 = (const float4*)gs2 + ((size_t)b*4 + hq)*DD;
  int r0 = tid >> 4, cg0 = tid & 15;
  float4 ld0, ld1, ld2, ld3, gld;
  float a0=0.f, a1=0.f, a2=0.f, a3=0.f, ssum=0.f, ssq=0.f;
#define LOADC(c) { const float* pb = xb + (c)*SDC; \
    ld0 = *(const float4*)(pb + (size_t)(r0+ 0)*DD + cg0*4); \
    ld1 = *(const float4*)(pb + (size_t)(r0+16)*DD + cg0*4); \
    ld2 = *(const float4*)(pb + (size_t)(r0+32)*DD + cg0*4); \
    ld3 = *(const float4*)(pb + (size_t)(r0+48)*DD + cg0*4); \
    gld = gq4[(c)*64 + row]; }
#define STOREC(c) { float4* tb2 = xt[(c)&1]; int u = cg0 ^ r0; \
    tb2[(r0+ 0)*16 + u] = ld0; \
    tb2[(r0+16)*16 + u] = ld1; \
    tb2[(r0+32)*16 + u] = ld2; \
    tb2[(r0+48)*16 + u] = ld3; \
    gt[(c)&1][hq*64 + row] = gld; }

  LOADC(0);
  STOREC(0);
  for (int c = 0; c < NCH; ++c){
    if (c+1 < NCH) LOADC(c+1);
    __syncthreads();
    {
      const float4* tb = xt[c&1] + row*16;
      const float4* gb = gt[c&1] + hq*64;
#pragma unroll 4
      for (int d4=0; d4<16; d4++){
        float4 xv = tb[d4 ^ rx];
        float4 g0 = gb[d4*4+0];
        float4 g1 = gb[d4*4+1];
        float4 g2 = gb[d4*4+2];
        float4 g3 = gb[d4*4+3];
        ssum += xv.x + xv.y + xv.z + xv.w;
        ssq = fmaf(xv.x,xv.x,ssq); ssq = fmaf(xv.y,xv.y,ssq);
        ssq = fmaf(xv.z,xv.z,ssq); ssq = fmaf(xv.w,xv.w,ssq);
        a0 = fmaf(xv.x,g0.x,a0); a1 = fmaf(xv.x,g0.y,a1);
        a2 = fmaf(xv.x,g0.z,a2); a3 = fmaf(xv.x,g0.w,a3);
        a0 = fmaf(xv.y,g1.x,a0); a1 = fmaf(xv.y,g1.y,a1);
        a2 = fmaf(xv.y,g1.z,a2); a3 = fmaf(xv.y,g1.w,a3);
        a0 = fmaf(xv.z,g2.x,a0); a1 = fmaf(xv.z,g2.y,a1);
        a2 = fmaf(xv.z,g2.z,a2); a3 = fmaf(xv.z,g2.w,a3);
        a0 = fmaf(xv.w,g3.x,a0); a1 = fmaf(xv.w,g3.y,a1);
        a2 = fmaf(xv.w,g3.z,a2); a3 = fmaf(xv.w,g3.w,a3);
      }
    }
    if (c+1 < NCH){
      __syncthreads();
      STOREC(c+1);
    }
  }
#undef LOADC
#undef STOREC
  float mu = ssum * (1.f/DD);
  float rs = rsqrtf(ssq*(1.f/DD) - mu*mu + EPS);
  int t = t0 + row;
  float4 gq = *(const float4*)(gsum + b*NH + hq*4);
  float4 cq = *(const float4*)(cst  + b*NH + hq*4);
  float4 sc;
  sc.x = (rs*(a0 - mu*gq.x) + cq.x)*0.125f;
  sc.y = (rs*(a1 - mu*gq.y) + cq.y)*0.125f;
  sc.z = (rs*(a2 - mu*gq.z) + cq.z)*0.125f;
  sc.w = (rs*(a3 - mu*gq.w) + cq.w)*0.125f;
  pacc[((size_t)b*4 + hq)*TT + t] = sc;
  if (hq == 0) rs_arr[(size_t)b*TT + t] = rs;

  bool act = (t < vb);
  float m0 = act ? sc.x : -3.0e38f;
  float m1 = act ? sc.y : -3.0e38f;
  float m2 = act ? sc.z : -3.0e38f;
  float m3 = act ? sc.w : -3.0e38f;
#pragma unroll
  for (int off=32; off>=1; off>>=1){
    m0 = fmaxf(m0, __shfl_xor(m0, off, 64));
    m1 = fmaxf(m1, __shfl_xor(m1, off, 64));
    m2 = fmaxf(m2, __shfl_xor(m2, off, 64));
    m3 = fmaxf(m3, __shfl_xor(m3, off, 64));
  }
  float rm = rs*mu;
  float e0 = act ? expf(sc.x - m0) : 0.f;
  float e1 = act ? expf(sc.y - m1) : 0.f;
  float e2 = act ? expf(sc.z - m2) : 0.f;
  float e3 = act ? expf(sc.w - m3) : 0.f;
  float S0=e0, S1=e1, S2=e2, S3=e3;
  float B0=e0*rm, B1=e1*rm, B2=e2*rm, B3=e3*rm;
#pragma unroll
  for (int off=32; off>=1; off>>=1){
    S0 += __shfl_xor(S0, off, 64);
    S1 += __shfl_xor(S1, off, 64);
    S2 += __shfl_xor(S2, off, 64);
    S3 += __shfl_xor(S3, off, 64);
    B0 += __shfl_xor(B0, off, 64);
    B1 += __shfl_xor(B1, off, 64);
    B2 += __shfl_xor(B2, off, 64);
    B3 += __shfl_xor(B3, off, 64);
  }
  if (row == 0){
    float* pb = pm + ((size_t)(b*(TT/SR) + tc)*3)*16 + hq*4;
    pb[0]=m0;  pb[1]=m1;  pb[2]=m2;  pb[3]=m3;
    pb[16]=S0; pb[17]=S1; pb[18]=S2; pb[19]=S3;
    pb[32]=B0; pb[33]=B1; pb[34]=B2; pb[35]=B3;
  }
}

// ------------- K3: partial u accumulation; in-block pm merge + inline alpha -------------
#define BODY4(XC, Q0, Q1, Q2, Q3) { \
  float aa[16]={(Q0).x,(Q0).y,(Q0).z,(Q0).w,(Q1).x,(Q1).y,(Q1).z,(Q1).w, \
                (Q2).x,(Q2).y,(Q2).z,(Q2).w,(Q3).x,(Q3).y,(Q3).z,(Q3).w}; \
  _Pragma("unroll") \
  for (int h=0;h<16;h++){ ax[h]=fmaf(aa[h],(XC).x,ax[h]); ay[h]=fmaf(aa[h],(XC).y,ay[h]); } }

__global__ __launch_bounds__(512, 4) void k_accum(
    const float* __restrict__ X, const float4* __restrict__ pacc,
    const float* __restrict__ rs_arr, const float* __restrict__ pm,
    const int* __restrict__ valid, float* __restrict__ part, int ct)
{
  int c = blockIdx.x, b = blockIdx.y;
  int tid = threadIdx.x;
  int t0 = c*ct;
  int vb = valid[b];
  if (t0 >= vb) return;
  int tend = min(vb, t0 + ct);
  float ax[16], ay[16];
#pragma unroll
  for (int h=0;h<16;h++){ ax[h]=0.f; ay[h]=0.f; }
  __shared__ float4 at[2][256];
  __shared__ float mrg[3][32][16];
  __shared__ float mf[16], ivf[16];
  // ---- in-block tree merge of chunk softmax partials (deterministic) ----
  {
    int nch = (vb + SR - 1)/SR;
    int cc = tid >> 4, hh = tid & 15;
    float M=-3.0e38f, S=0.f, Bv=0.f;
    if (cc < nch){
      const float* pb = pm + ((size_t)(b*(TT/SR) + cc))*48;
      M = pb[hh]; S = pb[16+hh]; Bv = pb[32+hh];
    }
    mrg[0][cc][hh]=M; mrg[1][cc][hh]=S; mrg[2][cc][hh]=Bv;
    __syncthreads();
#pragma unroll
    for (int str=16; str>=1; str>>=1){
      if (cc < str){
        float ma=mrg[0][cc][hh], mbv=mrg[0][cc+str][hh];
        float Mn=fmaxf(ma,mbv);
        float f1=expf(ma-Mn), f2=expf(mbv-Mn);
        mrg[1][cc][hh]=mrg[1][cc][hh]*f1+mrg[1][cc+str][hh]*f2;
        mrg[2][cc][hh]=mrg[2][cc][hh]*f1+mrg[2][cc+str][hh]*f2;
        mrg[0][cc][hh]=Mn;
      }
      __syncthreads();
    }
    if (tid < 16){ mf[tid]=mrg[0][0][tid]; ivf[tid]=1.f/mrg[1][0][tid]; }
    __syncthreads();
  }
  const float2* xb = (const float2*)(X + (size_t)b*TT*DD);
  int tl6 = tid & 63, hqa = tid >> 6;   // used when tid<256
  float4 m4 = make_float4(0.f,0.f,0.f,0.f), iv4 = m4, scv = m4;
  float rsv = 0.f;
  if (tid < 256){
    m4  = make_float4(mf[hqa*4+0], mf[hqa*4+1], mf[hqa*4+2], mf[hqa*4+3]);
    iv4 = make_float4(ivf[hqa*4+0], ivf[hqa*4+1], ivf[hqa*4+2], ivf[hqa*4+3]);
    scv = pacc[((size_t)b*4 + hqa)*TT + t0 + tl6];
    rsv = rs_arr[(size_t)b*TT + t0 + tl6];
    float4 al;
    al.x = expf(scv.x - m4.x) * rsv * iv4.x;
    al.y = expf(scv.y - m4.y) * rsv * iv4.y;
    al.z = expf(scv.z - m4.z) * rsv * iv4.z;
    al.w = expf(scv.w - m4.w) * rsv * iv4.w;
    at[0][tl6*4 + hqa] = al;   // [row][hq] layout — matches consumer
  }
  int nsub = (tend - t0 + 63) >> 6;
  for (int s=0; s<nsub; s++){
    if (s+1 < nsub && tid < 256){
      int tn = t0 + (s+1)*64 + tl6;
      scv = pacc[((size_t)b*4 + hqa)*TT + tn];
      rsv = rs_arr[(size_t)b*TT + tn];
    }
    __syncthreads();
    int ts = t0 + s*64;
    int te = min(tend - ts, 64);
    const float4* av = at[s&1];
    if (te == 64){
      size_t rb = (size_t)ts*(DD/2) + tid;
      float2 x0 = xb[rb], x1 = xb[rb+512], x2 = xb[rb+1024], x3 = xb[rb+1536];
      for (int tl=0; tl<64; tl+=4){
        float2 c0=x0, c1=x1, c2=x2, c3=x3;
        if (tl < 60){
          size_t nb = rb + (size_t)(tl+4)*512;
          x0 = xb[nb]; x1 = xb[nb+512]; x2 = xb[nb+1024]; x3 = xb[nb+1536];
        }
        float4 p00=av[(tl+0)*4+0], p01=av[(tl+0)*4+1], p02=av[(tl+0)*4+2], p03=av[(tl+0)*4+3];
        BODY4(c0, p00, p01, p02, p03);
        float4 p10=av[(tl+1)*4+0], p11=av[(tl+1)*4+1], p12=av[(tl+1)*4+2], p13=av[(tl+1)*4+3];
        BODY4(c1, p10, p11, p12, p13);
        float4 p20=av[(tl+2)*4+0], p21=av[(tl+2)*4+1], p22=av[(tl+2)*4+2], p23=av[(tl+2)*4+3];
        BODY4(c2, p20, p21, p22, p23);
        float4 p30=av[(tl+3)*4+0], p31=av[(tl+3)*4+1], p32=av[(tl+3)*4+2], p33=av[(tl+3)*4+3];
        BODY4(c3, p30, p31, p32, p33);
      }
    } else {
      for (int tl=0; tl<te; tl++){
        float2 xc = xb[(size_t)(ts+tl)*(DD/2) + tid];
        float4 p0=av[tl*4+0], p1=av[tl*4+1], p2=av[tl*4+2], p3=av[tl*4+3];
        BODY4(xc, p0, p1, p2, p3);
      }
    }
    if (s+1 < nsub){
      __syncthreads();
      if (tid < 256){
        float4 al;
        al.x = expf(scv.x - m4.x) * rsv * iv4.x;
        al.y = expf(scv.y - m4.y) * rsv * iv4.y;
        al.z = expf(scv.z - m4.z) * rsv * iv4.z;
        al.w = expf(scv.w - m4.w) * rsv * iv4.w;
        at[(s+1)&1][tl6*4 + hqa] = al;
      }
    }
  }
  float* pp = part + (((size_t)c*BB + b)*NH)*DD;
#pragma unroll
  for (int h=0;h<16;h++)
    *(float2*)(pp + (size_t)h*DD + tid*2) = make_float2(ax[h], ay[h]);
}

// ------------- K4: u-finalize (in-block beta merge) + ctx = Wv_h @ u + bv -------------
__global__ __launch_bounds__(256) void k_uctx(const float* __restrict__ part,
   const int* __restrict__ valid, const float* __restrict__ pm,
   const float* __restrict__ g_kv, const float* __restrict__ b_kv,
   const float* __restrict__ Wfull, const float* __restrict__ bfull,
   float* __restrict__ ctx, int ct, int nc)
{
  int h = blockIdx.x, b = blockIdx.y;
  int tid = threadIdx.x;
  __shared__ float ul[DD];
  __shared__ float Wl[64][65];
  __shared__ float red2[4][64];
  __shared__ float bsh;
  int vb = valid[b];
  // ---- wave-0 merge of pm -> beta (this h only) ----
  if (tid < 64){
    int nch = (vb + SR - 1)/SR;
    float M=-3.0e38f, S=0.f, Bv=0.f;
    if (tid < nch){
      const float* pb = pm + ((size_t)(b*(TT/SR) + tid))*48;
      M = pb[h]; S = pb[16+h]; Bv = pb[32+h];
    }
#pragma unroll
    for (int off=32; off>=1; off>>=1){
      float om = __shfl_down(M, off, 64);
      float oS = __shfl_down(S, off, 64);
      float oB = __shfl_down(Bv, off, 64);
      float Mn = fmaxf(M, om);
      float f1 = expf(M - Mn), f2 = expf(om - Mn);
      S  = S*f1 + oS*f2;
      Bv = Bv*f1 + oB*f2;
      M = Mn;
    }
    if (tid == 0) bsh = Bv * (1.f/S);
  }
  // ---- part sum (overlaps with merge) ----
  int nv = (vb + ct - 1) / ct;
  if (nv > nc) nv = nc;
  int d = tid*4;
  float4 s = make_float4(0.f,0.f,0.f,0.f);
  for (int c=0;c<nv;c++){
    float4 v = *(const float4*)(part + (((size_t)c*BB + b)*NH + h)*DD + d);
    s.x+=v.x; s.y+=v.y; s.z+=v.z; s.w+=v.w;
  }
  __syncthreads();
  {
    float be = bsh;
    float4 g = *(const float4*)(g_kv + d);
    float4 bv = *(const float4*)(b_kv + d);
    float4 r;
    r.x = fmaf(g.x, s.x-be, bv.x);
    r.y = fmaf(g.y, s.y-be, bv.y);
    r.z = fmaf(g.z, s.z-be, bv.z);
    r.w = fmaf(g.w, s.w-be, bv.w);
    ((float4*)ul)[tid] = r;
  }
  __syncthreads();
  int j = tid & 63, quart = tid >> 6;
  float acc = 0.f;
  const float* Wv = Wfull + (size_t)2*DD*DD;
  for (int dc=0; dc<DD; dc+=64){
#pragma unroll
    for (int p=0;p<4;p++){
      int fi = p*256 + tid, r = fi >> 4, q4 = fi & 15;
      float4 v = *(const float4*)(Wv + (size_t)(h*HDIM + r)*DD + dc + q4*4);
      Wl[r][q4*4+0]=v.x; Wl[r][q4*4+1]=v.y; Wl[r][q4*4+2]=v.z; Wl[r][q4*4+3]=v.w;
    }
    __syncthreads();
#pragma unroll
    for (int i=0;i<16;i++)
      acc = fmaf(Wl[j][quart*16+i], ul[dc + quart*16 + i], acc);
    __syncthreads();
  }
  red2[quart][j] = acc;
  __syncthreads();
  if (quart == 0){
    float v = red2[0][j] + red2[1][j] + red2[2][j] + red2[3][j];
    ctx[(size_t)b*DD + h*HDIM + j] = v + bfull[2*DD + h*HDIM + j];
  }
}

// ------------- K5: fused out-proj reduce + out = LN(o + h_t) -------------
__global__ __launch_bounds__(256) void k_outln(const float* __restrict__ p2,
   const float* __restrict__ obias, const float* __restrict__ h_t,
   const float* __restrict__ g, const float* __restrict__ bb,
   float* __restrict__ out)
{
  int b = blockIdx.x, tid = threadIdx.x;
  __shared__ float red[64];
  int e = tid*4;
  float4 a = *(const float4*)(obias + e);
#pragma unroll
  for (int k=0;k<8;k++){
    float4 v = *(const float4*)(p2 + ((size_t)k*BB + b)*DD + e);
    a.x+=v.x; a.y+=v.y; a.z+=v.z; a.w+=v.w;
  }
  float4 r = ((const float4*)(h_t + (size_t)b*DD))[tid];
  a.x+=r.x; a.y+=r.y; a.z+=r.z; a.w+=r.w;
  float s = a.x + a.y + a.z + a.w;
  s = bredSum(s, red);
  float mu = s * (1.f/DD);
  float d0=a.x-mu, d1=a.y-mu, d2=a.z-mu, d3=a.w-mu;
  float s2 = d0*d0 + d1*d1 + d2*d2 + d3*d3;
  s2 = bredSum(s2, red);
  float rs = rsqrtf(s2*(1.f/DD) + EPS);
  float4 gv = ((const float4*)g)[tid], bv = ((const float4*)bb)[tid];
  float4 ov;
  ov.x = fmaf(d0*rs, gv.x, bv.x);
  ov.y = fmaf(d1*rs, gv.y, bv.y);
  ov.z = fmaf(d2*rs, gv.z, bv.z);
  ov.w = fmaf(d3*rs, gv.w, bv.w);
  ((float4*)(out + (size_t)b*DD))[tid] = ov;
}

extern "C" void kernel_launch(void* const* d_in, const int* in_sizes, int n_in,
                              void* d_out, int out_size, void* d_ws, size_t ws_size,
                              hipStream_t stream) {
  const float* h_t     = (const float*)d_in[0];
  const float* H_p     = (const float*)d_in[1];
  const int*   valid   = (const int*)  d_in[2];
  const float* ln_q_g  = (const float*)d_in[3];
  const float* ln_q_b  = (const float*)d_in[4];
  const float* ln_kv_g = (const float*)d_in[5];
  const float* ln_kv_b = (const float*)d_in[6];
  const float* ln_out_g= (const float*)d_in[7];
  const float* ln_out_b= (const float*)d_in[8];
  const float* log_tau = (const float*)d_in[9];
  const float* in_w    = (const float*)d_in[10];
  const float* in_b    = (const float*)d_in[11];
  const float* out_w   = (const float*)d_in[12];
  const float* out_b   = (const float*)d_in[13];
  float* out = (float*)d_out;

  float* ws     = (float*)d_ws;
  float* q      = ws;
  float* gs2    = q      + BB*DD;
  float* gsum   = gs2    + (size_t)BB*DD*NH;
  float* cst    = gsum   + BB*NH;
  float* ctx    = cst    + BB*NH;
  float* rs_arr = ctx    + BB*DD;
  float* pm     = rs_arr + (size_t)BB*TT;
  float* paccf  = pm     + (size_t)BB*(TT/SR)*48;
  float* part   = paccf  + (size_t)BB*4*TT*4;   // pacc = 1,048,576 floats
  float4* pacc  = (float4*)paccf;
  // part region time-shared: in-proj gemm partials (consumed by k_prep_s),
  // accum partials (k_accum -> k_uctx), out-proj gemm partials (k_outln).

  size_t base_floats = (size_t)(part - ws);
  int nc = 16;
  if ((base_floats + (size_t)nc*BB*NH*DD) * sizeof(float) > ws_size) nc = 8;
  int ct = TT / nc;

  k_qln<<<BB, 256, 0, stream>>>(h_t, ln_q_g, ln_q_b, log_tau, q);
  k_gemmsplit<<<dim3(16,8), 256, 0, stream>>>(q, in_w, part);
  k_prep_s<<<dim3(NH,BB), 256, 0, stream>>>(part, in_w, in_b, ln_kv_g, ln_kv_b, gs2, gsum, cst);
  k_scores<<<dim3(TT/SR,BB), 256, 0, stream>>>(H_p, valid, gs2, gsum, cst, pacc, rs_arr, pm);
  k_accum<<<dim3(nc,BB), 512, 0, stream>>>(H_p, pacc, rs_arr, pm, valid, part, ct);
  k_uctx<<<dim3(NH,BB), 256, 0, stream>>>(part, valid, pm, ln_kv_g, ln_kv_b, in_w, in_b, ctx, ct, nc);
  k_gemmsplit<<<dim3(16,8), 256, 0, stream>>>(ctx, out_w, part);
  k_outln<<<BB, 256, 0, stream>>>(part, out_b, h_t, ln_out_g, ln_out_b, out);
}

// Round 15
// 131.489 us; speedup vs baseline: 1.9263x; 1.1183x over previous
//
#include <hip/hip_runtime.h>
#include <math.h>

#define BB 32
#define TT 2048
#define DD 1024
#define NH 16
#define HDIM 64
#define EPS 1e-5f

// ---------------- reduction helpers ----------------
__device__ __forceinline__ float wredSum(float v){
  v += __shfl_down(v, 32, 64);
  v += __shfl_down(v, 16, 64);
  v += __shfl_down(v, 8, 64);
  v += __shfl_down(v, 4, 64);
  v += __shfl_down(v, 2, 64);
  v += __shfl_down(v, 1, 64);
  return v;
}
__device__ float bredSum(float v, float* red){
  int lane = threadIdx.x & 63, w = threadIdx.x >> 6, nw = blockDim.x >> 6;
  v = wredSum(v);
  __syncthreads();
  if (lane == 0) red[w] = v;
  __syncthreads();
  if (w == 0){
    float x = (lane < nw) ? red[lane] : 0.f;
    x = wredSum(x);
    if (lane == 0) red[0] = x;
  }
  __syncthreads();
  return red[0];
}

// ---------------- K0a: q = LN(h_t)*tau ----------------
__global__ __launch_bounds__(256) void k_qln(const float* __restrict__ h_t,
   const float* __restrict__ g, const float* __restrict__ bb,
   const float* __restrict__ log_tau, float* __restrict__ q)
{
  int b = blockIdx.x, tid = threadIdx.x;
  __shared__ float red[64];
  float4 x = ((const float4*)(h_t + (size_t)b*DD))[tid];
  float s = x.x + x.y + x.z + x.w;
  s = bredSum(s, red);
  float mu = s * (1.f/DD);
  float d0=x.x-mu, d1=x.y-mu, d2=x.z-mu, d3=x.w-mu;
  float s2 = d0*d0 + d1*d1 + d2*d2 + d3*d3;
  s2 = bredSum(s2, red);
  float rs = rsqrtf(s2*(1.f/DD) + EPS);
  float tau = fminf(fmaxf(expf(log_tau[0]), 0.25f), 4.0f);
  float4 gv = ((const float4*)g)[tid], bv = ((const float4*)bb)[tid];
  float4 o;
  o.x = (d0*rs*gv.x + bv.x)*tau;
  o.y = (d1*rs*gv.y + bv.y)*tau;
  o.z = (d2*rs*gv.z + bv.z)*tau;
  o.w = (d3*rs*gv.w + bv.w)*tau;
  ((float4*)(q + (size_t)b*DD))[tid] = o;
}

// ------------- worklist: compact (b,chunk) pairs for k_scores / k_accum -------------
#define SR 64
__global__ __launch_bounds__(64) void k_worklist(const int* __restrict__ valid,
    int* __restrict__ wl_s, int* __restrict__ wl_a, int* __restrict__ hdr, int ct)
{
  int lane = threadIdx.x;
  int b = lane & 31;
  bool isA = lane >= 32;
  int vb = valid[b];
  int n = isA ? (vb + ct - 1)/ct : (vb + SR - 1)/SR;
  int off = n;
#pragma unroll
  for (int d = 1; d < 32; d <<= 1){
    int o = __shfl_up(off, d, 32);   // segment width 32: halves independent
    if ((lane & 31) >= d) off += o;
  }
  int start = off - n;
  int* wl = isA ? wl_a : wl_s;
  for (int c = 0; c < n; c++) wl[start + c] = (b << 16) | c;
  if ((lane & 31) == 31) hdr[isA ? 1 : 0] = off;
}

// ------------- small GEMM (32x1024 @ 1024x1024^T), d-split partials -------------
__global__ __launch_bounds__(256) void k_gemmsplit(const float* __restrict__ A,
    const float* __restrict__ W, float* __restrict__ p2)
{
  int ec = blockIdx.x, ds = blockIdx.y;
  int tid = threadIdx.x;
  __shared__ float Wl[64][132];
  __shared__ float Al[32][132];
  int d0 = ds*128, e0 = ec*64;
#pragma unroll
  for (int p=0;p<8;p++){
    int fi = p*256 + tid, r = fi >> 5, q4 = fi & 31;
    float4 v = *(const float4*)(W + (size_t)(e0+r)*DD + d0 + q4*4);
    *(float4*)&Wl[r][q4*4] = v;
  }
#pragma unroll
  for (int p=0;p<4;p++){
    int fi = p*256 + tid, r = fi >> 5, q4 = fi & 31;
    float4 v = *(const float4*)(A + (size_t)r*DD + d0 + q4*4);
    *(float4*)&Al[r][q4*4] = v;
  }
  __syncthreads();
  int eL = tid & 63, bg = tid >> 6;
  float acc[8];
#pragma unroll
  for (int i=0;i<8;i++) acc[i]=0.f;
  for (int d4=0; d4<32; d4++){
    float4 w = *(float4*)&Wl[eL][d4*4];
#pragma unroll
    for (int i=0;i<8;i++){
      float4 a = *(float4*)&Al[bg*8+i][d4*4];
      acc[i] = fmaf(w.x, a.x, acc[i]);
      acc[i] = fmaf(w.y, a.y, acc[i]);
      acc[i] = fmaf(w.z, a.z, acc[i]);
      acc[i] = fmaf(w.w, a.w, acc[i]);
    }
  }
#pragma unroll
  for (int i=0;i<8;i++)
    p2[((size_t)ds*BB + (bg*8+i))*DD + e0 + eL] = acc[i];
}

// ------------- K0c: qh-reduce + s = Wk_h^T qh_h ; gs2, gsum, cst -------------
__global__ __launch_bounds__(256) void k_prep_s(const float* __restrict__ p2,
    const float* __restrict__ Wfull, const float* __restrict__ bfull,
    const float* __restrict__ g_kv, const float* __restrict__ b_kv,
    float* __restrict__ gs2, float* __restrict__ gsum, float* __restrict__ cst)
{
  int h = blockIdx.x, b = blockIdx.y;
  int tid = threadIdx.x;
  __shared__ float qhl[64];
  __shared__ float red[64];
  if (tid < 64){
    float s = bfull[h*HDIM + tid];   // bq
#pragma unroll
    for (int k=0;k<8;k++)
      s += p2[((size_t)k*BB + b)*DD + h*HDIM + tid];
    qhl[tid] = s;
  }
  __syncthreads();
  int d0 = tid*4;
  const float* Wk = Wfull + (size_t)DD*DD + (size_t)h*HDIM*DD + d0;
  float4 acc = make_float4(0.f,0.f,0.f,0.f);
#pragma unroll
  for (int j=0;j<64;j++){
    float qv = qhl[j];
    float4 w = *(const float4*)(Wk + (size_t)j*DD);
    acc.x = fmaf(qv, w.x, acc.x);
    acc.y = fmaf(qv, w.y, acc.y);
    acc.z = fmaf(qv, w.z, acc.z);
    acc.w = fmaf(qv, w.w, acc.w);
  }
  float4 gk = *(const float4*)(g_kv + d0);
  float4 bk = *(const float4*)(b_kv + d0);
  float4 gsv;
  gsv.x = acc.x*gk.x; gsv.y = acc.y*gk.y;
  gsv.z = acc.z*gk.z; gsv.w = acc.w*gk.w;
  int hq = h >> 2, hj = h & 3;
  float* gp = gs2 + (((size_t)b*4 + hq)*DD + d0)*4 + hj;
  gp[0] = gsv.x; gp[4] = gsv.y; gp[8] = gsv.z; gp[12] = gsv.w;
  float lgs = gsv.x + gsv.y + gsv.z + gsv.w;
  float lbs = acc.x*bk.x + acc.y*bk.y + acc.z*bk.z + acc.w*bk.w;
  float lc = 0.f;
  if (tid < 64) lc = qhl[tid] * bfull[DD + h*HDIM + tid];  // qh . bk-bias
  float tg = bredSum(lgs, red);
  float tb = bredSum(lbs + lc, red);
  if (tid == 0){ gsum[b*NH+h] = tg; cst[b*NH+h] = tb; }
}

// ------------- K1: full-D scores + chunk-partial online softmax (worklist) -------------
#define SDC 64
#define NCH (DD/SDC)
__global__ __launch_bounds__(256, 4) void k_scores(
    const float* __restrict__ X, const int* __restrict__ valid,
    const int* __restrict__ wl, const int* __restrict__ hdr,
    const float* __restrict__ gs2, const float* __restrict__ gsum,
    const float* __restrict__ cst,
    float4* __restrict__ pacc, float* __restrict__ rs_arr,
    float* __restrict__ pm)
{
  int i = blockIdx.x;
  if (i >= hdr[0]) return;
  int wv = wl[i];
  int b = wv >> 16, tc = wv & 0xffff;
  int t0 = tc * SR;
  int vb = valid[b];
  int tid = threadIdx.x;
  int row = tid & 63, rx = row & 15;
  int hq = __builtin_amdgcn_readfirstlane(tid >> 6);
  __shared__ float4 xt[2][SR*16];    // 16KB x2, swizzle u = cg ^ (r&15)
  __shared__ float4 gt[2][4*64];     // 4KB x2: [hq][d]
  const float* xb = X + ((size_t)b*TT + t0)*DD;
  const float4* gq4 = (const float4*)gs2 + ((size_t)b*4 + hq)*DD;
  int r0 = tid >> 4, cg0 = tid & 15;
  float4 ld0, ld1, ld2, ld3, gld;
  float a0=0.f, a1=0.f, a2=0.f, a3=0.f, ssum=0.f, ssq=0.f;
#define LOADC(c) { const float* pb = xb + (c)*SDC; \
    ld0 = *(const float4*)(pb + (size_t)(r0+ 0)*DD + cg0*4); \
    ld1 = *(const float4*)(pb + (size_t)(r0+16)*DD + cg0*4); \
    ld2 = *(const float4*)(pb + (size_t)(r0+32)*DD + cg0*4); \
    ld3 = *(const float4*)(pb + (size_t)(r0+48)*DD + cg0*4); \
    gld = gq4[(c)*64 + row]; }
#define STOREC(c) { float4* tb2 = xt[(c)&1]; int u = cg0 ^ r0; \
    tb2[(r0+ 0)*16 + u] = ld0; \
    tb2[(r0+16)*16 + u] = ld1; \
    tb2[(r0+32)*16 + u] = ld2; \
    tb2[(r0+48)*16 + u] = ld3; \
    gt[(c)&1][hq*64 + row] = gld; }

  LOADC(0);
  STOREC(0);
  for (int c = 0; c < NCH; ++c){
    if (c+1 < NCH) LOADC(c+1);
    __syncthreads();
    {
      const float4* tb = xt[c&1] + row*16;
      const float4* gb = gt[c&1] + hq*64;
#pragma unroll 4
      for (int d4=0; d4<16; d4++){
        float4 xv = tb[d4 ^ rx];
        float4 g0 = gb[d4*4+0];
        float4 g1 = gb[d4*4+1];
        float4 g2 = gb[d4*4+2];
        float4 g3 = gb[d4*4+3];
        ssum += xv.x + xv.y + xv.z + xv.w;
        ssq = fmaf(xv.x,xv.x,ssq); ssq = fmaf(xv.y,xv.y,ssq);
        ssq = fmaf(xv.z,xv.z,ssq); ssq = fmaf(xv.w,xv.w,ssq);
        a0 = fmaf(xv.x,g0.x,a0); a1 = fmaf(xv.x,g0.y,a1);
        a2 = fmaf(xv.x,g0.z,a2); a3 = fmaf(xv.x,g0.w,a3);
        a0 = fmaf(xv.y,g1.x,a0); a1 = fmaf(xv.y,g1.y,a1);
        a2 = fmaf(xv.y,g1.z,a2); a3 = fmaf(xv.y,g1.w,a3);
        a0 = fmaf(xv.z,g2.x,a0); a1 = fmaf(xv.z,g2.y,a1);
        a2 = fmaf(xv.z,g2.z,a2); a3 = fmaf(xv.z,g2.w,a3);
        a0 = fmaf(xv.w,g3.x,a0); a1 = fmaf(xv.w,g3.y,a1);
        a2 = fmaf(xv.w,g3.z,a2); a3 = fmaf(xv.w,g3.w,a3);
      }
    }
    if (c+1 < NCH){
      __syncthreads();
      STOREC(c+1);
    }
  }
#undef LOADC
#undef STOREC
  float mu = ssum * (1.f/DD);
  float rs = rsqrtf(ssq*(1.f/DD) - mu*mu + EPS);
  int t = t0 + row;
  float4 gq = *(const float4*)(gsum + b*NH + hq*4);
  float4 cq = *(const float4*)(cst  + b*NH + hq*4);
  float4 sc;
  sc.x = (rs*(a0 - mu*gq.x) + cq.x)*0.125f;
  sc.y = (rs*(a1 - mu*gq.y) + cq.y)*0.125f;
  sc.z = (rs*(a2 - mu*gq.z) + cq.z)*0.125f;
  sc.w = (rs*(a3 - mu*gq.w) + cq.w)*0.125f;
  pacc[((size_t)b*4 + hq)*TT + t] = sc;
  if (hq == 0) rs_arr[(size_t)b*TT + t] = rs;

  bool act = (t < vb);
  float m0 = act ? sc.x : -3.0e38f;
  float m1 = act ? sc.y : -3.0e38f;
  float m2 = act ? sc.z : -3.0e38f;
  float m3 = act ? sc.w : -3.0e38f;
#pragma unroll
  for (int off=32; off>=1; off>>=1){
    m0 = fmaxf(m0, __shfl_xor(m0, off, 64));
    m1 = fmaxf(m1, __shfl_xor(m1, off, 64));
    m2 = fmaxf(m2, __shfl_xor(m2, off, 64));
    m3 = fmaxf(m3, __shfl_xor(m3, off, 64));
  }
  float rm = rs*mu;
  float e0 = act ? expf(sc.x - m0) : 0.f;
  float e1 = act ? expf(sc.y - m1) : 0.f;
  float e2 = act ? expf(sc.z - m2) : 0.f;
  float e3 = act ? expf(sc.w - m3) : 0.f;
  float S0=e0, S1=e1, S2=e2, S3=e3;
  float B0=e0*rm, B1=e1*rm, B2=e2*rm, B3=e3*rm;
#pragma unroll
  for (int off=32; off>=1; off>>=1){
    S0 += __shfl_xor(S0, off, 64);
    S1 += __shfl_xor(S1, off, 64);
    S2 += __shfl_xor(S2, off, 64);
    S3 += __shfl_xor(S3, off, 64);
    B0 += __shfl_xor(B0, off, 64);
    B1 += __shfl_xor(B1, off, 64);
    B2 += __shfl_xor(B2, off, 64);
    B3 += __shfl_xor(B3, off, 64);
  }
  if (row == 0){
    float* pb = pm + ((size_t)(b*(TT/SR) + tc)*3)*16 + hq*4;
    pb[0]=m0;  pb[1]=m1;  pb[2]=m2;  pb[3]=m3;
    pb[16]=S0; pb[17]=S1; pb[18]=S2; pb[19]=S3;
    pb[32]=B0; pb[33]=B1; pb[34]=B2; pb[35]=B3;
  }
}

// ------------- K3: partial u accumulation (worklist); in-block pm merge + inline alpha -------------
#define BODY4(XC, Q0, Q1, Q2, Q3) { \
  float aa[16]={(Q0).x,(Q0).y,(Q0).z,(Q0).w,(Q1).x,(Q1).y,(Q1).z,(Q1).w, \
                (Q2).x,(Q2).y,(Q2).z,(Q2).w,(Q3).x,(Q3).y,(Q3).z,(Q3).w}; \
  _Pragma("unroll") \
  for (int h=0;h<16;h++){ ax[h]=fmaf(aa[h],(XC).x,ax[h]); ay[h]=fmaf(aa[h],(XC).y,ay[h]); } }

__global__ __launch_bounds__(512, 4) void k_accum(
    const float* __restrict__ X, const float4* __restrict__ pacc,
    const float* __restrict__ rs_arr, const float* __restrict__ pm,
    const int* __restrict__ valid, const int* __restrict__ wl,
    const int* __restrict__ hdr, float* __restrict__ part, int ct)
{
  int i = blockIdx.x;
  if (i >= hdr[1]) return;
  int wv = wl[i];
  int b = wv >> 16, c = wv & 0xffff;
  int tid = threadIdx.x;
  int t0 = c*ct;
  int vb = valid[b];
  int tend = min(vb, t0 + ct);
  float ax[16], ay[16];
#pragma unroll
  for (int h=0;h<16;h++){ ax[h]=0.f; ay[h]=0.f; }
  __shared__ float4 at[2][256];
  __shared__ float mrg[3][32][16];
  __shared__ float mf[16], ivf[16];
  // ---- in-block tree merge of chunk softmax partials (deterministic) ----
  {
    int nch = (vb + SR - 1)/SR;
    int cc = tid >> 4, hh = tid & 15;
    float M=-3.0e38f, S=0.f, Bv=0.f;
    if (cc < nch){
      const float* pb = pm + ((size_t)(b*(TT/SR) + cc))*48;
      M = pb[hh]; S = pb[16+hh]; Bv = pb[32+hh];
    }
    mrg[0][cc][hh]=M; mrg[1][cc][hh]=S; mrg[2][cc][hh]=Bv;
    __syncthreads();
#pragma unroll
    for (int str=16; str>=1; str>>=1){
      if (cc < str){
        float ma=mrg[0][cc][hh], mbv=mrg[0][cc+str][hh];
        float Mn=fmaxf(ma,mbv);
        float f1=expf(ma-Mn), f2=expf(mbv-Mn);
        mrg[1][cc][hh]=mrg[1][cc][hh]*f1+mrg[1][cc+str][hh]*f2;
        mrg[2][cc][hh]=mrg[2][cc][hh]*f1+mrg[2][cc+str][hh]*f2;
        mrg[0][cc][hh]=Mn;
      }
      __syncthreads();
    }
    if (tid < 16){ mf[tid]=mrg[0][0][tid]; ivf[tid]=1.f/mrg[1][0][tid]; }
    __syncthreads();
  }
  const float2* xb = (const float2*)(X + (size_t)b*TT*DD);
  int tl6 = tid & 63, hqa = tid >> 6;   // used when tid<256
  float4 m4 = make_float4(0.f,0.f,0.f,0.f), iv4 = m4, scv = m4;
  float rsv = 0.f;
  if (tid < 256){
    m4  = make_float4(mf[hqa*4+0], mf[hqa*4+1], mf[hqa*4+2], mf[hqa*4+3]);
    iv4 = make_float4(ivf[hqa*4+0], ivf[hqa*4+1], ivf[hqa*4+2], ivf[hqa*4+3]);
    scv = pacc[((size_t)b*4 + hqa)*TT + t0 + tl6];
    rsv = rs_arr[(size_t)b*TT + t0 + tl6];
    float4 al;
    al.x = expf(scv.x - m4.x) * rsv * iv4.x;
    al.y = expf(scv.y - m4.y) * rsv * iv4.y;
    al.z = expf(scv.z - m4.z) * rsv * iv4.z;
    al.w = expf(scv.w - m4.w) * rsv * iv4.w;
    at[0][tl6*4 + hqa] = al;   // [row][hq] layout — matches consumer
  }
  int nsub = (tend - t0 + 63) >> 6;
  for (int s=0; s<nsub; s++){
    if (s+1 < nsub && tid < 256){
      int tn = t0 + (s+1)*64 + tl6;
      scv = pacc[((size_t)b*4 + hqa)*TT + tn];
      rsv = rs_arr[(size_t)b*TT + tn];
    }
    __syncthreads();
    int ts = t0 + s*64;
    int te = min(tend - ts, 64);
    const float4* av = at[s&1];
    if (te == 64){
      size_t rb = (size_t)ts*(DD/2) + tid;
      float2 x0 = xb[rb], x1 = xb[rb+512], x2 = xb[rb+1024], x3 = xb[rb+1536];
      for (int tl=0; tl<64; tl+=4){
        float2 c0=x0, c1=x1, c2=x2, c3=x3;
        if (tl < 60){
          size_t nb = rb + (size_t)(tl+4)*512;
          x0 = xb[nb]; x1 = xb[nb+512]; x2 = xb[nb+1024]; x3 = xb[nb+1536];
        }
        float4 p00=av[(tl+0)*4+0], p01=av[(tl+0)*4+1], p02=av[(tl+0)*4+2], p03=av[(tl+0)*4+3];
        BODY4(c0, p00, p01, p02, p03);
        float4 p10=av[(tl+1)*4+0], p11=av[(tl+1)*4+1], p12=av[(tl+1)*4+2], p13=av[(tl+1)*4+3];
        BODY4(c1, p10, p11, p12, p13);
        float4 p20=av[(tl+2)*4+0], p21=av[(tl+2)*4+1], p22=av[(tl+2)*4+2], p23=av[(tl+2)*4+3];
        BODY4(c2, p20, p21, p22, p23);
        float4 p30=av[(tl+3)*4+0], p31=av[(tl+3)*4+1], p32=av[(tl+3)*4+2], p33=av[(tl+3)*4+3];
        BODY4(c3, p30, p31, p32, p33);
      }
    } else {
      for (int tl=0; tl<te; tl++){
        float2 xc = xb[(size_t)(ts+tl)*(DD/2) + tid];
        float4 p0=av[tl*4+0], p1=av[tl*4+1], p2=av[tl*4+2], p3=av[tl*4+3];
        BODY4(xc, p0, p1, p2, p3);
      }
    }
    if (s+1 < nsub){
      __syncthreads();
      if (tid < 256){
        float4 al;
        al.x = expf(scv.x - m4.x) * rsv * iv4.x;
        al.y = expf(scv.y - m4.y) * rsv * iv4.y;
        al.z = expf(scv.z - m4.z) * rsv * iv4.z;
        al.w = expf(scv.w - m4.w) * rsv * iv4.w;
        at[(s+1)&1][tl6*4 + hqa] = al;
      }
    }
  }
  float* pp = part + (((size_t)c*BB + b)*NH)*DD;
#pragma unroll
  for (int h=0;h<16;h++)
    *(float2*)(pp + (size_t)h*DD + tid*2) = make_float2(ax[h], ay[h]);
}

// ------------- K4: u-finalize (in-block beta merge) + ctx = Wv_h @ u + bv -------------
__global__ __launch_bounds__(256) void k_uctx(const float* __restrict__ part,
   const int* __restrict__ valid, const float* __restrict__ pm,
   const float* __restrict__ g_kv, const float* __restrict__ b_kv,
   const float* __restrict__ Wfull, const float* __restrict__ bfull,
   float* __restrict__ ctx, int ct, int nc)
{
  int h = blockIdx.x, b = blockIdx.y;
  int tid = threadIdx.x;
  __shared__ float ul[DD];
  __shared__ float Wl[64][65];
  __shared__ float red2[4][64];
  __shared__ float bsh;
  int vb = valid[b];
  // ---- wave-0 merge of pm -> beta (this h only) ----
  if (tid < 64){
    int nch = (vb + SR - 1)/SR;
    float M=-3.0e38f, S=0.f, Bv=0.f;
    if (tid < nch){
      const float* pb = pm + ((size_t)(b*(TT/SR) + tid))*48;
      M = pb[h]; S = pb[16+h]; Bv = pb[32+h];
    }
#pragma unroll
    for (int off=32; off>=1; off>>=1){
      float om = __shfl_down(M, off, 64);
      float oS = __shfl_down(S, off, 64);
      float oB = __shfl_down(Bv, off, 64);
      float Mn = fmaxf(M, om);
      float f1 = expf(M - Mn), f2 = expf(om - Mn);
      S  = S*f1 + oS*f2;
      Bv = Bv*f1 + oB*f2;
      M = Mn;
    }
    if (tid == 0) bsh = Bv * (1.f/S);
  }
  // ---- part sum (overlaps with merge) ----
  int nv = (vb + ct - 1) / ct;
  if (nv > nc) nv = nc;
  int d = tid*4;
  float4 s = make_float4(0.f,0.f,0.f,0.f);
  for (int c=0;c<nv;c++){
    float4 v = *(const float4*)(part + (((size_t)c*BB + b)*NH + h)*DD + d);
    s.x+=v.x; s.y+=v.y; s.z+=v.z; s.w+=v.w;
  }
  __syncthreads();
  {
    float be = bsh;
    float4 g = *(const float4*)(g_kv + d);
    float4 bv = *(const float4*)(b_kv + d);
    float4 r;
    r.x = fmaf(g.x, s.x-be, bv.x);
    r.y = fmaf(g.y, s.y-be, bv.y);
    r.z = fmaf(g.z, s.z-be, bv.z);
    r.w = fmaf(g.w, s.w-be, bv.w);
    ((float4*)ul)[tid] = r;
  }
  __syncthreads();
  int j = tid & 63, quart = tid >> 6;
  float acc = 0.f;
  const float* Wv = Wfull + (size_t)2*DD*DD;
  for (int dc=0; dc<DD; dc+=64){
#pragma unroll
    for (int p=0;p<4;p++){
      int fi = p*256 + tid, r = fi >> 4, q4 = fi & 15;
      float4 v = *(const float4*)(Wv + (size_t)(h*HDIM + r)*DD + dc + q4*4);
      Wl[r][q4*4+0]=v.x; Wl[r][q4*4+1]=v.y; Wl[r][q4*4+2]=v.z; Wl[r][q4*4+3]=v.w;
    }
    __syncthreads();
#pragma unroll
    for (int i=0;i<16;i++)
      acc = fmaf(Wl[j][quart*16+i], ul[dc + quart*16 + i], acc);
    __syncthreads();
  }
  red2[quart][j] = acc;
  __syncthreads();
  if (quart == 0){
    float v = red2[0][j] + red2[1][j] + red2[2][j] + red2[3][j];
    ctx[(size_t)b*DD + h*HDIM + j] = v + bfull[2*DD + h*HDIM + j];
  }
}

// ------------- K5: fused out-proj reduce + out = LN(o + h_t) -------------
__global__ __launch_bounds__(256) void k_outln(const float* __restrict__ p2,
   const float* __restrict__ obias, const float* __restrict__ h_t,
   const float* __restrict__ g, const float* __restrict__ bb,
   float* __restrict__ out)
{
  int b = blockIdx.x, tid = threadIdx.x;
  __shared__ float red[64];
  int e = tid*4;
  float4 a = *(const float4*)(obias + e);
#pragma unroll
  for (int k=0;k<8;k++){
    float4 v = *(const float4*)(p2 + ((size_t)k*BB + b)*DD + e);
    a.x+=v.x; a.y+=v.y; a.z+=v.z; a.w+=v.w;
  }
  float4 r = ((const float4*)(h_t + (size_t)b*DD))[tid];
  a.x+=r.x; a.y+=r.y; a.z+=r.z; a.w+=r.w;
  float s = a.x + a.y + a.z + a.w;
  s = bredSum(s, red);
  float mu = s * (1.f/DD);
  float d0=a.x-mu, d1=a.y-mu, d2=a.z-mu, d3=a.w-mu;
  float s2 = d0*d0 + d1*d1 + d2*d2 + d3*d3;
  s2 = bredSum(s2, red);
  float rs = rsqrtf(s2*(1.f/DD) + EPS);
  float4 gv = ((const float4*)g)[tid], bv = ((const float4*)bb)[tid];
  float4 ov;
  ov.x = fmaf(d0*rs, gv.x, bv.x);
  ov.y = fmaf(d1*rs, gv.y, bv.y);
  ov.z = fmaf(d2*rs, gv.z, bv.z);
  ov.w = fmaf(d3*rs, gv.w, bv.w);
  ((float4*)(out + (size_t)b*DD))[tid] = ov;
}

extern "C" void kernel_launch(void* const* d_in, const int* in_sizes, int n_in,
                              void* d_out, int out_size, void* d_ws, size_t ws_size,
                              hipStream_t stream) {
  const float* h_t     = (const float*)d_in[0];
  const float* H_p     = (const float*)d_in[1];
  const int*   valid   = (const int*)  d_in[2];
  const float* ln_q_g  = (const float*)d_in[3];
  const float* ln_q_b  = (const float*)d_in[4];
  const float* ln_kv_g = (const float*)d_in[5];
  const float* ln_kv_b = (const float*)d_in[6];
  const float* ln_out_g= (const float*)d_in[7];
  const float* ln_out_b= (const float*)d_in[8];
  const float* log_tau = (const float*)d_in[9];
  const float* in_w    = (const float*)d_in[10];
  const float* in_b    = (const float*)d_in[11];
  const float* out_w   = (const float*)d_in[12];
  const float* out_b   = (const float*)d_in[13];
  float* out = (float*)d_out;

  float* ws     = (float*)d_ws;
  float* q      = ws;
  float* gs2    = q      + BB*DD;
  float* gsum   = gs2    + (size_t)BB*DD*NH;
  float* cst    = gsum   + BB*NH;
  float* ctx    = cst    + BB*NH;
  float* rs_arr = ctx    + BB*DD;
  float* pm     = rs_arr + (size_t)BB*TT;
  int*   wl_s   = (int*)(pm + (size_t)BB*(TT/SR)*48);
  int*   wl_a   = wl_s + 1024;
  int*   hdr    = wl_a + 512;
  float* paccf  = (float*)(hdr + 64);   // aligned spare
  float* part   = paccf  + (size_t)BB*4*TT*4;   // pacc = 1,048,576 floats
  float4* pacc  = (float4*)paccf;
  // part region time-shared: in-proj gemm partials (consumed by k_prep_s),
  // accum partials (k_accum -> k_uctx), out-proj gemm partials (k_outln).

  size_t base_floats = (size_t)(part - ws);
  int nc = 16;
  if ((base_floats + (size_t)nc*BB*NH*DD) * sizeof(float) > ws_size) nc = 8;
  int ct = TT / nc;

  k_worklist<<<1, 64, 0, stream>>>(valid, wl_s, wl_a, hdr, ct);
  k_qln<<<BB, 256, 0, stream>>>(h_t, ln_q_g, ln_q_b, log_tau, q);
  k_gemmsplit<<<dim3(16,8), 256, 0, stream>>>(q, in_w, part);
  k_prep_s<<<dim3(NH,BB), 256, 0, stream>>>(part, in_w, in_b, ln_kv_g, ln_kv_b, gs2, gsum, cst);
  k_scores<<<(TT/SR)*BB, 256, 0, stream>>>(H_p, valid, wl_s, hdr, gs2, gsum, cst, pacc, rs_arr, pm);
  k_accum<<<nc*BB, 512, 0, stream>>>(H_p, pacc, rs_arr, pm, valid, wl_a, hdr, part, ct);
  k_uctx<<<dim3(NH,BB), 256, 0, stream>>>(part, valid, pm, ln_kv_g, ln_kv_b, in_w, in_b, ctx, ct, nc);
  k_gemmsplit<<<dim3(16,8), 256, 0, stream>>>(ctx, out_w, part);
  k_outln<<<BB, 256, 0, stream>>>(part, out_b, h_t, ln_out_g, ln_out_b, out);
}

// Round 16
// 122.433 us; speedup vs baseline: 2.0688x; 1.0740x over previous
//
#include <hip/hip_runtime.h>
#include <math.h>

#define BB 32
#define TT 2048
#define DD 1024
#define NH 16
#define HDIM 64
#define EPS 1e-5f
#define SR 64

// ---------------- reduction helpers ----------------
__device__ __forceinline__ float wredSum(float v){
  v += __shfl_down(v, 32, 64);
  v += __shfl_down(v, 16, 64);
  v += __shfl_down(v, 8, 64);
  v += __shfl_down(v, 4, 64);
  v += __shfl_down(v, 2, 64);
  v += __shfl_down(v, 1, 64);
  return v;
}
__device__ float bredSum(float v, float* red){
  int lane = threadIdx.x & 63, w = threadIdx.x >> 6, nw = blockDim.x >> 6;
  v = wredSum(v);
  __syncthreads();
  if (lane == 0) red[w] = v;
  __syncthreads();
  if (w == 0){
    float x = (lane < nw) ? red[lane] : 0.f;
    x = wredSum(x);
    if (lane == 0) red[0] = x;
  }
  __syncthreads();
  return red[0];
}

// ---------------- K0a: q = LN(h_t)*tau  (+ fused worklist in block BB) ----------------
__global__ __launch_bounds__(256) void k_qln(const float* __restrict__ h_t,
   const float* __restrict__ g, const float* __restrict__ bb,
   const float* __restrict__ log_tau, float* __restrict__ q,
   const int* __restrict__ valid, int* __restrict__ wl_s,
   int* __restrict__ wl_a, int* __restrict__ hdr, int ct)
{
  int b = blockIdx.x, tid = threadIdx.x;
  if (b == BB){
    if (tid < 64){
      int lane = tid;
      int b2 = lane & 31;
      bool isA = lane >= 32;
      int vb = valid[b2];
      int n = isA ? (vb + ct - 1)/ct : (vb + SR - 1)/SR;
      int off = n;
#pragma unroll
      for (int d = 1; d < 32; d <<= 1){
        int o = __shfl_up(off, d, 32);   // width 32: halves independent
        if ((lane & 31) >= d) off += o;
      }
      int start = off - n;
      int* wl = isA ? wl_a : wl_s;
      for (int c = 0; c < n; c++) wl[start + c] = (b2 << 16) | c;
      if ((lane & 31) == 31) hdr[isA ? 1 : 0] = off;
    }
    return;
  }
  __shared__ float red[64];
  float4 x = ((const float4*)(h_t + (size_t)b*DD))[tid];
  float s = x.x + x.y + x.z + x.w;
  s = bredSum(s, red);
  float mu = s * (1.f/DD);
  float d0=x.x-mu, d1=x.y-mu, d2=x.z-mu, d3=x.w-mu;
  float s2 = d0*d0 + d1*d1 + d2*d2 + d3*d3;
  s2 = bredSum(s2, red);
  float rs = rsqrtf(s2*(1.f/DD) + EPS);
  float tau = fminf(fmaxf(expf(log_tau[0]), 0.25f), 4.0f);
  float4 gv = ((const float4*)g)[tid], bv = ((const float4*)bb)[tid];
  float4 o;
  o.x = (d0*rs*gv.x + bv.x)*tau;
  o.y = (d1*rs*gv.y + bv.y)*tau;
  o.z = (d2*rs*gv.z + bv.z)*tau;
  o.w = (d3*rs*gv.w + bv.w)*tau;
  ((float4*)(q + (size_t)b*DD))[tid] = o;
}

// ------------- small GEMM (32x1024 @ 1024x1024^T), finer tiles: 32e x 128d -------------
// grid (32, 8), 256 threads, ~34KB LDS -> 4 blocks/CU.
__global__ __launch_bounds__(256) void k_gemmsplit(const float* __restrict__ A,
    const float* __restrict__ W, float* __restrict__ p2)
{
  int ec = blockIdx.x, ds = blockIdx.y;
  int tid = threadIdx.x;
  __shared__ float Wl[32][132];
  __shared__ float Al[32][132];
  int d0 = ds*128, e0 = ec*32;
#pragma unroll
  for (int p=0;p<4;p++){
    int fi = p*256 + tid, r = fi >> 5, q4 = fi & 31;
    float4 v = *(const float4*)(W + (size_t)(e0+r)*DD + d0 + q4*4);
    *(float4*)&Wl[r][q4*4] = v;
  }
#pragma unroll
  for (int p=0;p<4;p++){
    int fi = p*256 + tid, r = fi >> 5, q4 = fi & 31;
    float4 v = *(const float4*)(A + (size_t)r*DD + d0 + q4*4);
    *(float4*)&Al[r][q4*4] = v;
  }
  __syncthreads();
  int eL = tid & 31, bg = tid >> 5;   // 8 groups x 4 b-rows
  float acc[4];
#pragma unroll
  for (int i=0;i<4;i++) acc[i]=0.f;
  for (int d4=0; d4<32; d4++){
    float4 w = *(float4*)&Wl[eL][d4*4];
#pragma unroll
    for (int i=0;i<4;i++){
      float4 a = *(float4*)&Al[bg*4+i][d4*4];
      acc[i] = fmaf(w.x, a.x, acc[i]);
      acc[i] = fmaf(w.y, a.y, acc[i]);
      acc[i] = fmaf(w.z, a.z, acc[i]);
      acc[i] = fmaf(w.w, a.w, acc[i]);
    }
  }
#pragma unroll
  for (int i=0;i<4;i++)
    p2[((size_t)ds*BB + (bg*4+i))*DD + e0 + eL] = acc[i];
}

// ------------- K0c: qh-reduce + s = Wk_h^T qh_h ; gs2, gsum, cst -------------
__global__ __launch_bounds__(256) void k_prep_s(const float* __restrict__ p2,
    const float* __restrict__ Wfull, const float* __restrict__ bfull,
    const float* __restrict__ g_kv, const float* __restrict__ b_kv,
    float* __restrict__ gs2, float* __restrict__ gsum, float* __restrict__ cst)
{
  int h = blockIdx.x, b = blockIdx.y;
  int tid = threadIdx.x;
  __shared__ float qhl[64];
  __shared__ float red[64];
  if (tid < 64){
    float s = bfull[h*HDIM + tid];   // bq
#pragma unroll
    for (int k=0;k<8;k++)
      s += p2[((size_t)k*BB + b)*DD + h*HDIM + tid];
    qhl[tid] = s;
  }
  __syncthreads();
  int d0 = tid*4;
  const float* Wk = Wfull + (size_t)DD*DD + (size_t)h*HDIM*DD + d0;
  float4 acc = make_float4(0.f,0.f,0.f,0.f);
#pragma unroll
  for (int j=0;j<64;j++){
    float qv = qhl[j];
    float4 w = *(const float4*)(Wk + (size_t)j*DD);
    acc.x = fmaf(qv, w.x, acc.x);
    acc.y = fmaf(qv, w.y, acc.y);
    acc.z = fmaf(qv, w.z, acc.z);
    acc.w = fmaf(qv, w.w, acc.w);
  }
  float4 gk = *(const float4*)(g_kv + d0);
  float4 bk = *(const float4*)(b_kv + d0);
  float4 gsv;
  gsv.x = acc.x*gk.x; gsv.y = acc.y*gk.y;
  gsv.z = acc.z*gk.z; gsv.w = acc.w*gk.w;
  int hq = h >> 2, hj = h & 3;
  float* gp = gs2 + (((size_t)b*4 + hq)*DD + d0)*4 + hj;
  gp[0] = gsv.x; gp[4] = gsv.y; gp[8] = gsv.z; gp[12] = gsv.w;
  float lgs = gsv.x + gsv.y + gsv.z + gsv.w;
  float lbs = acc.x*bk.x + acc.y*bk.y + acc.z*bk.z + acc.w*bk.w;
  float lc = 0.f;
  if (tid < 64) lc = qhl[tid] * bfull[DD + h*HDIM + tid];  // qh . bk-bias
  float tg = bredSum(lgs, red);
  float tb = bredSum(lbs + lc, red);
  if (tid == 0){ gsum[b*NH+h] = tg; cst[b*NH+h] = tb; }
}

// ------------- K1: full-D scores + chunk-partial online softmax (worklist) -------------
#define SDC 64
#define NCH (DD/SDC)
__global__ __launch_bounds__(256, 4) void k_scores(
    const float* __restrict__ X, const int* __restrict__ valid,
    const int* __restrict__ wl, const int* __restrict__ hdr,
    const float* __restrict__ gs2, const float* __restrict__ gsum,
    const float* __restrict__ cst,
    float4* __restrict__ pacc, float* __restrict__ rs_arr,
    float* __restrict__ pm)
{
  int i = blockIdx.x;
  if (i >= hdr[0]) return;
  int wv = wl[i];
  int b = wv >> 16, tc = wv & 0xffff;
  int t0 = tc * SR;
  int vb = valid[b];
  int tid = threadIdx.x;
  int row = tid & 63, rx = row & 15;
  int hq = __builtin_amdgcn_readfirstlane(tid >> 6);
  __shared__ float4 xt[2][SR*16];    // 16KB x2, swizzle u = cg ^ (r&15)
  __shared__ float4 gt[2][4*64];     // 4KB x2: [hq][d]
  const float* xb = X + ((size_t)b*TT + t0)*DD;
  const float4* gq4 = (const float4*)gs2 + ((size_t)b*4 + hq)*DD;
  int r0 = tid >> 4, cg0 = tid & 15;
  float4 ld0, ld1, ld2, ld3, gld;
  float a0=0.f, a1=0.f, a2=0.f, a3=0.f, ssum=0.f, ssq=0.f;
#define LOADC(c) { const float* pb = xb + (c)*SDC; \
    ld0 = *(const float4*)(pb + (size_t)(r0+ 0)*DD + cg0*4); \
    ld1 = *(const float4*)(pb + (size_t)(r0+16)*DD + cg0*4); \
    ld2 = *(const float4*)(pb + (size_t)(r0+32)*DD + cg0*4); \
    ld3 = *(const float4*)(pb + (size_t)(r0+48)*DD + cg0*4); \
    gld = gq4[(c)*64 + row]; }
#define STOREC(c) { float4* tb2 = xt[(c)&1]; int u = cg0 ^ r0; \
    tb2[(r0+ 0)*16 + u] = ld0; \
    tb2[(r0+16)*16 + u] = ld1; \
    tb2[(r0+32)*16 + u] = ld2; \
    tb2[(r0+48)*16 + u] = ld3; \
    gt[(c)&1][hq*64 + row] = gld; }

  LOADC(0);
  STOREC(0);
  for (int c = 0; c < NCH; ++c){
    if (c+1 < NCH) LOADC(c+1);
    __syncthreads();
    {
      const float4* tb = xt[c&1] + row*16;
      const float4* gb = gt[c&1] + hq*64;
#pragma unroll 4
      for (int d4=0; d4<16; d4++){
        float4 xv = tb[d4 ^ rx];
        float4 g0 = gb[d4*4+0];
        float4 g1 = gb[d4*4+1];
        float4 g2 = gb[d4*4+2];
        float4 g3 = gb[d4*4+3];
        ssum += xv.x + xv.y + xv.z + xv.w;
        ssq = fmaf(xv.x,xv.x,ssq); ssq = fmaf(xv.y,xv.y,ssq);
        ssq = fmaf(xv.z,xv.z,ssq); ssq = fmaf(xv.w,xv.w,ssq);
        a0 = fmaf(xv.x,g0.x,a0); a1 = fmaf(xv.x,g0.y,a1);
        a2 = fmaf(xv.x,g0.z,a2); a3 = fmaf(xv.x,g0.w,a3);
        a0 = fmaf(xv.y,g1.x,a0); a1 = fmaf(xv.y,g1.y,a1);
        a2 = fmaf(xv.y,g1.z,a2); a3 = fmaf(xv.y,g1.w,a3);
        a0 = fmaf(xv.z,g2.x,a0); a1 = fmaf(xv.z,g2.y,a1);
        a2 = fmaf(xv.z,g2.z,a2); a3 = fmaf(xv.z,g2.w,a3);
        a0 = fmaf(xv.w,g3.x,a0); a1 = fmaf(xv.w,g3.y,a1);
        a2 = fmaf(xv.w,g3.z,a2); a3 = fmaf(xv.w,g3.w,a3);
      }
    }
    if (c+1 < NCH){
      __syncthreads();
      STOREC(c+1);
    }
  }
#undef LOADC
#undef STOREC
  float mu = ssum * (1.f/DD);
  float rs = rsqrtf(ssq*(1.f/DD) - mu*mu + EPS);
  int t = t0 + row;
  float4 gq = *(const float4*)(gsum + b*NH + hq*4);
  float4 cq = *(const float4*)(cst  + b*NH + hq*4);
  float4 sc;
  sc.x = (rs*(a0 - mu*gq.x) + cq.x)*0.125f;
  sc.y = (rs*(a1 - mu*gq.y) + cq.y)*0.125f;
  sc.z = (rs*(a2 - mu*gq.z) + cq.z)*0.125f;
  sc.w = (rs*(a3 - mu*gq.w) + cq.w)*0.125f;
  pacc[((size_t)b*4 + hq)*TT + t] = sc;
  if (hq == 0) rs_arr[(size_t)b*TT + t] = rs;

  bool act = (t < vb);
  float m0 = act ? sc.x : -3.0e38f;
  float m1 = act ? sc.y : -3.0e38f;
  float m2 = act ? sc.z : -3.0e38f;
  float m3 = act ? sc.w : -3.0e38f;
#pragma unroll
  for (int off=32; off>=1; off>>=1){
    m0 = fmaxf(m0, __shfl_xor(m0, off, 64));
    m1 = fmaxf(m1, __shfl_xor(m1, off, 64));
    m2 = fmaxf(m2, __shfl_xor(m2, off, 64));
    m3 = fmaxf(m3, __shfl_xor(m3, off, 64));
  }
  float rm = rs*mu;
  float e0 = act ? expf(sc.x - m0) : 0.f;
  float e1 = act ? expf(sc.y - m1) : 0.f;
  float e2 = act ? expf(sc.z - m2) : 0.f;
  float e3 = act ? expf(sc.w - m3) : 0.f;
  float S0=e0, S1=e1, S2=e2, S3=e3;
  float B0=e0*rm, B1=e1*rm, B2=e2*rm, B3=e3*rm;
#pragma unroll
  for (int off=32; off>=1; off>>=1){
    S0 += __shfl_xor(S0, off, 64);
    S1 += __shfl_xor(S1, off, 64);
    S2 += __shfl_xor(S2, off, 64);
    S3 += __shfl_xor(S3, off, 64);
    B0 += __shfl_xor(B0, off, 64);
    B1 += __shfl_xor(B1, off, 64);
    B2 += __shfl_xor(B2, off, 64);
    B3 += __shfl_xor(B3, off, 64);
  }
  if (row == 0){
    float* pb = pm + ((size_t)(b*(TT/SR) + tc)*3)*16 + hq*4;
    pb[0]=m0;  pb[1]=m1;  pb[2]=m2;  pb[3]=m3;
    pb[16]=S0; pb[17]=S1; pb[18]=S2; pb[19]=S3;
    pb[32]=B0; pb[33]=B1; pb[34]=B2; pb[35]=B3;
  }
}

// ------------- K3: partial u accumulation (worklist); in-block pm merge + inline alpha -------------
#define BODY4(XC, Q0, Q1, Q2, Q3) { \
  float aa[16]={(Q0).x,(Q0).y,(Q0).z,(Q0).w,(Q1).x,(Q1).y,(Q1).z,(Q1).w, \
                (Q2).x,(Q2).y,(Q2).z,(Q2).w,(Q3).x,(Q3).y,(Q3).z,(Q3).w}; \
  _Pragma("unroll") \
  for (int h=0;h<16;h++){ ax[h]=fmaf(aa[h],(XC).x,ax[h]); ay[h]=fmaf(aa[h],(XC).y,ay[h]); } }

__global__ __launch_bounds__(512, 4) void k_accum(
    const float* __restrict__ X, const float4* __restrict__ pacc,
    const float* __restrict__ rs_arr, const float* __restrict__ pm,
    const int* __restrict__ valid, const int* __restrict__ wl,
    const int* __restrict__ hdr, float* __restrict__ part, int ct)
{
  int i = blockIdx.x;
  if (i >= hdr[1]) return;
  int wv = wl[i];
  int b = wv >> 16, c = wv & 0xffff;
  int tid = threadIdx.x;
  int t0 = c*ct;
  int vb = valid[b];
  int tend = min(vb, t0 + ct);
  float ax[16], ay[16];
#pragma unroll
  for (int h=0;h<16;h++){ ax[h]=0.f; ay[h]=0.f; }
  __shared__ float4 at[2][256];
  __shared__ float mrg[3][32][16];
  __shared__ float mf[16], ivf[16];
  // ---- in-block tree merge of chunk softmax partials (deterministic) ----
  {
    int nch = (vb + SR - 1)/SR;
    int cc = tid >> 4, hh = tid & 15;
    float M=-3.0e38f, S=0.f, Bv=0.f;
    if (cc < nch){
      const float* pb = pm + ((size_t)(b*(TT/SR) + cc))*48;
      M = pb[hh]; S = pb[16+hh]; Bv = pb[32+hh];
    }
    mrg[0][cc][hh]=M; mrg[1][cc][hh]=S; mrg[2][cc][hh]=Bv;
    __syncthreads();
#pragma unroll
    for (int str=16; str>=1; str>>=1){
      if (cc < str){
        float ma=mrg[0][cc][hh], mbv=mrg[0][cc+str][hh];
        float Mn=fmaxf(ma,mbv);
        float f1=expf(ma-Mn), f2=expf(mbv-Mn);
        mrg[1][cc][hh]=mrg[1][cc][hh]*f1+mrg[1][cc+str][hh]*f2;
        mrg[2][cc][hh]=mrg[2][cc][hh]*f1+mrg[2][cc+str][hh]*f2;
        mrg[0][cc][hh]=Mn;
      }
      __syncthreads();
    }
    if (tid < 16){ mf[tid]=mrg[0][0][tid]; ivf[tid]=1.f/mrg[1][0][tid]; }
    __syncthreads();
  }
  const float2* xb = (const float2*)(X + (size_t)b*TT*DD);
  int tl6 = tid & 63, hqa = tid >> 6;   // used when tid<256
  float4 m4 = make_float4(0.f,0.f,0.f,0.f), iv4 = m4, scv = m4;
  float rsv = 0.f;
  if (tid < 256){
    m4  = make_float4(mf[hqa*4+0], mf[hqa*4+1], mf[hqa*4+2], mf[hqa*4+3]);
    iv4 = make_float4(ivf[hqa*4+0], ivf[hqa*4+1], ivf[hqa*4+2], ivf[hqa*4+3]);
    scv = pacc[((size_t)b*4 + hqa)*TT + t0 + tl6];
    rsv = rs_arr[(size_t)b*TT + t0 + tl6];
    float4 al;
    al.x = expf(scv.x - m4.x) * rsv * iv4.x;
    al.y = expf(scv.y - m4.y) * rsv * iv4.y;
    al.z = expf(scv.z - m4.z) * rsv * iv4.z;
    al.w = expf(scv.w - m4.w) * rsv * iv4.w;
    at[0][tl6*4 + hqa] = al;   // [row][hq] layout — matches consumer
  }
  int nsub = (tend - t0 + 63) >> 6;
  for (int s=0; s<nsub; s++){
    if (s+1 < nsub && tid < 256){
      int tn = t0 + (s+1)*64 + tl6;
      scv = pacc[((size_t)b*4 + hqa)*TT + tn];
      rsv = rs_arr[(size_t)b*TT + tn];
    }
    __syncthreads();
    int ts = t0 + s*64;
    int te = min(tend - ts, 64);
    const float4* av = at[s&1];
    if (te == 64){
      size_t rb = (size_t)ts*(DD/2) + tid;
      float2 x0 = xb[rb], x1 = xb[rb+512], x2 = xb[rb+1024], x3 = xb[rb+1536];
      for (int tl=0; tl<64; tl+=4){
        float2 c0=x0, c1=x1, c2=x2, c3=x3;
        if (tl < 60){
          size_t nb = rb + (size_t)(tl+4)*512;
          x0 = xb[nb]; x1 = xb[nb+512]; x2 = xb[nb+1024]; x3 = xb[nb+1536];
        }
        float4 p00=av[(tl+0)*4+0], p01=av[(tl+0)*4+1], p02=av[(tl+0)*4+2], p03=av[(tl+0)*4+3];
        BODY4(c0, p00, p01, p02, p03);
        float4 p10=av[(tl+1)*4+0], p11=av[(tl+1)*4+1], p12=av[(tl+1)*4+2], p13=av[(tl+1)*4+3];
        BODY4(c1, p10, p11, p12, p13);
        float4 p20=av[(tl+2)*4+0], p21=av[(tl+2)*4+1], p22=av[(tl+2)*4+2], p23=av[(tl+2)*4+3];
        BODY4(c2, p20, p21, p22, p23);
        float4 p30=av[(tl+3)*4+0], p31=av[(tl+3)*4+1], p32=av[(tl+3)*4+2], p33=av[(tl+3)*4+3];
        BODY4(c3, p30, p31, p32, p33);
      }
    } else {
      for (int tl=0; tl<te; tl++){
        float2 xc = xb[(size_t)(ts+tl)*(DD/2) + tid];
        float4 p0=av[tl*4+0], p1=av[tl*4+1], p2=av[tl*4+2], p3=av[tl*4+3];
        BODY4(xc, p0, p1, p2, p3);
      }
    }
    if (s+1 < nsub){
      __syncthreads();
      if (tid < 256){
        float4 al;
        al.x = expf(scv.x - m4.x) * rsv * iv4.x;
        al.y = expf(scv.y - m4.y) * rsv * iv4.y;
        al.z = expf(scv.z - m4.z) * rsv * iv4.z;
        al.w = expf(scv.w - m4.w) * rsv * iv4.w;
        at[(s+1)&1][tl6*4 + hqa] = al;
      }
    }
  }
  float* pp = part + (((size_t)c*BB + b)*NH)*DD;
#pragma unroll
  for (int h=0;h<16;h++)
    *(float2*)(pp + (size_t)h*DD + tid*2) = make_float2(ax[h], ay[h]);
}

// ------------- K4: u-finalize (in-block beta merge) + ctx = Wv_h @ u + bv -------------
__global__ __launch_bounds__(256) void k_uctx(const float* __restrict__ part,
   const int* __restrict__ valid, const float* __restrict__ pm,
   const float* __restrict__ g_kv, const float* __restrict__ b_kv,
   const float* __restrict__ Wfull, const float* __restrict__ bfull,
   float* __restrict__ ctx, int ct, int nc)
{
  int h = blockIdx.x, b = blockIdx.y;
  int tid = threadIdx.x;
  __shared__ float ul[DD];
  __shared__ float Wl[64][65];
  __shared__ float red2[4][64];
  __shared__ float bsh;
  int vb = valid[b];
  // ---- wave-0 merge of pm -> beta (this h only) ----
  if (tid < 64){
    int nch = (vb + SR - 1)/SR;
    float M=-3.0e38f, S=0.f, Bv=0.f;
    if (tid < nch){
      const float* pb = pm + ((size_t)(b*(TT/SR) + tid))*48;
      M = pb[h]; S = pb[16+h]; Bv = pb[32+h];
    }
#pragma unroll
    for (int off=32; off>=1; off>>=1){
      float om = __shfl_down(M, off, 64);
      float oS = __shfl_down(S, off, 64);
      float oB = __shfl_down(Bv, off, 64);
      float Mn = fmaxf(M, om);
      float f1 = expf(M - Mn), f2 = expf(om - Mn);
      S  = S*f1 + oS*f2;
      Bv = Bv*f1 + oB*f2;
      M = Mn;
    }
    if (tid == 0) bsh = Bv * (1.f/S);
  }
  // ---- part sum (overlaps with merge) ----
  int nv = (vb + ct - 1) / ct;
  if (nv > nc) nv = nc;
  int d = tid*4;
  float4 s = make_float4(0.f,0.f,0.f,0.f);
  for (int c=0;c<nv;c++){
    float4 v = *(const float4*)(part + (((size_t)c*BB + b)*NH + h)*DD + d);
    s.x+=v.x; s.y+=v.y; s.z+=v.z; s.w+=v.w;
  }
  __syncthreads();
  {
    float be = bsh;
    float4 g = *(const float4*)(g_kv + d);
    float4 bv = *(const float4*)(b_kv + d);
    float4 r;
    r.x = fmaf(g.x, s.x-be, bv.x);
    r.y = fmaf(g.y, s.y-be, bv.y);
    r.z = fmaf(g.z, s.z-be, bv.z);
    r.w = fmaf(g.w, s.w-be, bv.w);
    ((float4*)ul)[tid] = r;
  }
  __syncthreads();
  int j = tid & 63, quart = tid >> 6;
  float acc = 0.f;
  const float* Wv = Wfull + (size_t)2*DD*DD;
  for (int dc=0; dc<DD; dc+=64){
#pragma unroll
    for (int p=0;p<4;p++){
      int fi = p*256 + tid, r = fi >> 4, q4 = fi & 15;
      float4 v = *(const float4*)(Wv + (size_t)(h*HDIM + r)*DD + dc + q4*4);
      Wl[r][q4*4+0]=v.x; Wl[r][q4*4+1]=v.y; Wl[r][q4*4+2]=v.z; Wl[r][q4*4+3]=v.w;
    }
    __syncthreads();
#pragma unroll
    for (int i=0;i<16;i++)
      acc = fmaf(Wl[j][quart*16+i], ul[dc + quart*16 + i], acc);
    __syncthreads();
  }
  red2[quart][j] = acc;
  __syncthreads();
  if (quart == 0){
    float v = red2[0][j] + red2[1][j] + red2[2][j] + red2[3][j];
    ctx[(size_t)b*DD + h*HDIM + j] = v + bfull[2*DD + h*HDIM + j];
  }
}

// ------------- K5: fused out-proj reduce + out = LN(o + h_t) -------------
__global__ __launch_bounds__(256) void k_outln(const float* __restrict__ p2,
   const float* __restrict__ obias, const float* __restrict__ h_t,
   const float* __restrict__ g, const float* __restrict__ bb,
   float* __restrict__ out)
{
  int b = blockIdx.x, tid = threadIdx.x;
  __shared__ float red[64];
  int e = tid*4;
  float4 a = *(const float4*)(obias + e);
#pragma unroll
  for (int k=0;k<8;k++){
    float4 v = *(const float4*)(p2 + ((size_t)k*BB + b)*DD + e);
    a.x+=v.x; a.y+=v.y; a.z+=v.z; a.w+=v.w;
  }
  float4 r = ((const float4*)(h_t + (size_t)b*DD))[tid];
  a.x+=r.x; a.y+=r.y; a.z+=r.z; a.w+=r.w;
  float s = a.x + a.y + a.z + a.w;
  s = bredSum(s, red);
  float mu = s * (1.f/DD);
  float d0=a.x-mu, d1=a.y-mu, d2=a.z-mu, d3=a.w-mu;
  float s2 = d0*d0 + d1*d1 + d2*d2 + d3*d3;
  s2 = bredSum(s2, red);
  float rs = rsqrtf(s2*(1.f/DD) + EPS);
  float4 gv = ((const float4*)g)[tid], bv = ((const float4*)bb)[tid];
  float4 ov;
  ov.x = fmaf(d0*rs, gv.x, bv.x);
  ov.y = fmaf(d1*rs, gv.y, bv.y);
  ov.z = fmaf(d2*rs, gv.z, bv.z);
  ov.w = fmaf(d3*rs, gv.w, bv.w);
  ((float4*)(out + (size_t)b*DD))[tid] = ov;
}

extern "C" void kernel_launch(void* const* d_in, const int* in_sizes, int n_in,
                              void* d_out, int out_size, void* d_ws, size_t ws_size,
                              hipStream_t stream) {
  const float* h_t     = (const float*)d_in[0];
  const float* H_p     = (const float*)d_in[1];
  const int*   valid   = (const int*)  d_in[2];
  const float* ln_q_g  = (const float*)d_in[3];
  const float* ln_q_b  = (const float*)d_in[4];
  const float* ln_kv_g = (const float*)d_in[5];
  const float* ln_kv_b = (const float*)d_in[6];
  const float* ln_out_g= (const float*)d_in[7];
  const float* ln_out_b= (const float*)d_in[8];
  const float* log_tau = (const float*)d_in[9];
  const float* in_w    = (const float*)d_in[10];
  const float* in_b    = (const float*)d_in[11];
  const float* out_w   = (const float*)d_in[12];
  const float* out_b   = (const float*)d_in[13];
  float* out = (float*)d_out;

  float* ws     = (float*)d_ws;
  float* q      = ws;
  float* gs2    = q      + BB*DD;
  float* gsum   = gs2    + (size_t)BB*DD*NH;
  float* cst    = gsum   + BB*NH;
  float* ctx    = cst    + BB*NH;
  float* rs_arr = ctx    + BB*DD;
  float* pm     = rs_arr + (size_t)BB*TT;
  int*   wl_s   = (int*)(pm + (size_t)BB*(TT/SR)*48);
  int*   wl_a   = wl_s + 1024;
  int*   hdr    = wl_a + 1024;
  float* paccf  = (float*)(hdr + 64);   // aligned spare
  float* part   = paccf  + (size_t)BB*4*TT*4;   // pacc = 1,048,576 floats
  float4* pacc  = (float4*)paccf;
  // part region time-shared: in-proj gemm partials (consumed by k_prep_s),
  // accum partials (k_accum -> k_uctx), out-proj gemm partials (k_outln).

  size_t base_floats = (size_t)(part - ws);
  int nc = 32;
  if ((base_floats + (size_t)nc*BB*NH*DD) * sizeof(float) > ws_size) nc = 16;
  int ct = TT / nc;

  k_qln<<<BB+1, 256, 0, stream>>>(h_t, ln_q_g, ln_q_b, log_tau, q, valid, wl_s, wl_a, hdr, ct);
  k_gemmsplit<<<dim3(32,8), 256, 0, stream>>>(q, in_w, part);
  k_prep_s<<<dim3(NH,BB), 256, 0, stream>>>(part, in_w, in_b, ln_kv_g, ln_kv_b, gs2, gsum, cst);
  k_scores<<<(TT/SR)*BB, 256, 0, stream>>>(H_p, valid, wl_s, hdr, gs2, gsum, cst, pacc, rs_arr, pm);
  k_accum<<<nc*BB, 512, 0, stream>>>(H_p, pacc, rs_arr, pm, valid, wl_a, hdr, part, ct);
  k_uctx<<<dim3(NH,BB), 256, 0, stream>>>(part, valid, pm, ln_kv_g, ln_kv_b, in_w, in_b, ctx, ct, nc);
  k_gemmsplit<<<dim3(32,8), 256, 0, stream>>>(ctx, out_w, part);
  k_outln<<<BB, 256, 0, stream>>>(part, out_b, h_t, ln_out_g, ln_out_b, out);
}